// Round 17
// baseline (1098.209 us; speedup 1.0000x reference)
//
#include <hip/hip_runtime.h>
#include <hip/hip_bf16.h>

#define S_LEN 1024
#define DIN 4096
#define NH 32
#define NG 8
#define HD 128

typedef __bf16 bf16x8 __attribute__((ext_vector_type(8)));
typedef __bf16 bf16x4 __attribute__((ext_vector_type(4)));
typedef float f32x4 __attribute__((ext_vector_type(4)));

__device__ __forceinline__ void gload_lds16(const void* g, void* l) {
  __builtin_amdgcn_global_load_lds(
      (const __attribute__((address_space(1))) unsigned int*)g,
      (__attribute__((address_space(3))) unsigned int*)l, 16, 0, 0);
}

__device__ __forceinline__ unsigned pack2bf(float a, float b) {
  union { __bf16 h[2]; unsigned u; } x;
  x.h[0] = (__bf16)a; x.h[1] = (__bf16)b;
  return x.u;
}

// ---------------- cast x: f32 -> bf16 (the only prep) ----------------
__global__ __launch_bounds__(256) void k_cast(const float* __restrict__ in,
                                              __bf16* __restrict__ out, int n4) {
  int i = blockIdx.x * 256 + threadIdx.x;
  if (i >= n4) return;
  const float4 v = ((const float4*)in)[i];
  bf16x4 o;
  o.x = (__bf16)v.x; o.y = (__bf16)v.y; o.z = (__bf16)v.z; o.w = (__bf16)v.w;
  ((bf16x4*)out)[i] = o;
}

// ---------------- RoPE, vectorized: 4 d-pairs per thread ----------------
__global__ __launch_bounds__(256) void k_rope(__bf16* __restrict__ Q, __bf16* __restrict__ Kb,
                                              const float* __restrict__ cosT,
                                              const float* __restrict__ sinT) {
  int idx = blockIdx.x * 256 + threadIdx.x;
  int d = (idx & 15) * 4;
  int row = idx >> 4;
  __bf16* p; int s;
  if (row < S_LEN * NH) { p = Q + (size_t)row * HD; s = row >> 5; }
  else { int r = row - S_LEN * NH; p = Kb + (size_t)r * HD; s = r >> 3; }
  const float4 c = *(const float4*)&cosT[s * HD + d];
  const float4 sn = *(const float4*)&sinT[s * HD + d];
  bf16x4 a = *(const bf16x4*)&p[d];
  bf16x4 b = *(const bf16x4*)&p[d + 64];
  bf16x4 oa, ob;
  oa.x = (__bf16)((float)a.x * c.x - (float)b.x * sn.x);
  oa.y = (__bf16)((float)a.y * c.y - (float)b.y * sn.y);
  oa.z = (__bf16)((float)a.z * c.z - (float)b.z * sn.z);
  oa.w = (__bf16)((float)a.w * c.w - (float)b.w * sn.w);
  ob.x = (__bf16)((float)b.x * c.x + (float)a.x * sn.x);
  ob.y = (__bf16)((float)b.y * c.y + (float)a.y * sn.y);
  ob.z = (__bf16)((float)b.z * c.z + (float)a.z * sn.z);
  ob.w = (__bf16)((float)b.w * c.w + (float)a.w * sn.w);
  *(bf16x4*)&p[d] = oa;
  *(bf16x4*)&p[d + 64] = ob;
}

// ---------------- GEMM: C(M,N) = A(M,K,bf16) * W(K,N,f32) ----------------
// BM=256 (MR=4), BN=64, BK=64. 4 waves, wave w owns rows [w*64,(w+1)*64).
// r16 post-mortem: every model except TLP falsified. The vmcnt(0)-at-barrier
// stall is structural (m97/m114); cross-block TLP is the only working fill.
// NEW = hybrid of the two proven bests:
//   r2's single-buffered 2-barrier cadence (801 TF @ 3 blk/CU)
//   + r14's f32-B reg-staging + MR=4 W-reuse
//   at 4 BLOCKS/CU: LDS 40KB (As 32 + Bp 8), launch_bounds(256,4).
// B(t+1) loads issue at top of compute(t) (regs, no LDS hazard) -> one full
// compute phase of flight. A DMA latency covered by 4-block TLP.
// B: k-pair packed dwords, b128 to Bp[kp][16c][4] at cphys=(nn>>2)^(kp&7)
//    [r10-PROVEN 0 conflicts]. Frag: 4 b32, 32 banks x 2-way (free).
// A: DMA-staged bf16, XOR chunk swizzle (proven 0-conflict).
// MODE 0: f32 C, grid (64,4). MODE 1: QKV split epilogue, grid (96,4).
template <int MODE, int MR>
__global__ __launch_bounds__(256, 4)
void k_gemm(const __bf16* __restrict__ A,
            const float* __restrict__ W0,
            const float* __restrict__ W1,
            const float* __restrict__ W2,
            float* __restrict__ C,
            __bf16* __restrict__ Qb,
            __bf16* __restrict__ Kb,
            __bf16* __restrict__ Vt) {
  __shared__ __bf16 As[MR * 64 * 64];     // 32 KB (MR=4)
  __shared__ unsigned Bp[32 * 64];        // 8 KB
  const int bm = blockIdx.y, bn = blockIdx.x;
  const int K = DIN, NT = K / 64;

  const float* Wsrc; int ldb, nloc;
  if (MODE == 0) { Wsrc = W0; ldb = 4096; nloc = bn * 64; }
  else {
    if (bn < 64)      { Wsrc = W0; ldb = 4096; nloc = bn * 64; }
    else if (bn < 80) { Wsrc = W1; ldb = 1024; nloc = (bn - 64) * 64; }
    else              { Wsrc = W2; ldb = 1024; nloc = (bn - 80) * 64; }
  }

  const int tid = threadIdx.x, w = tid >> 6;
  const int l = tid & 63, l15 = l & 15, g4 = l >> 4;

  const __bf16* Asrc = A + (size_t)(bm * MR * 64) * K;

  f32x4 acc[MR][4];
#pragma unroll
  for (int i = 0; i < MR; ++i)
#pragma unroll
    for (int j = 0; j < 4; ++j)
#pragma unroll
      for (int r = 0; r < 4; ++r) acc[i][j][r] = 0.f;

  // B staging: TWO named reg sets, alternated by 2x-unrolled loop (rule #20)
  float4 bregA[2][2], bregB[2][2];
  const int kp_s[2] = {tid >> 4, 16 + (tid >> 4)};
  const int nn_s = (tid & 15) * 4;

  auto loadB = [&](int t, float4 (&br)[2][2]) {
    if (t >= NT) return;
#pragma unroll
    for (int p = 0; p < 2; ++p) {
      const float* src = Wsrc + (size_t)(t * 64 + 2 * kp_s[p]) * ldb + nloc + nn_s;
      br[p][0] = *(const float4*)src;
      br[p][1] = *(const float4*)(src + ldb);
    }
  };
  auto writeB = [&](float4 (&br)[2][2]) {
#pragma unroll
    for (int p = 0; p < 2; ++p) {
      int kp = kp_s[p];
      int cphys = (nn_s >> 2) ^ (kp & 7);
      uint4 d;
      d.x = pack2bf(br[p][0].x, br[p][1].x);
      d.y = pack2bf(br[p][0].y, br[p][1].y);
      d.z = pack2bf(br[p][0].z, br[p][1].z);
      d.w = pack2bf(br[p][0].w, br[p][1].w);
      *(uint4*)&Bp[kp * 64 + cphys * 4] = d;
    }
  };
  auto issueA = [&](int t) {
#pragma unroll
    for (int p = 0; p < MR * 2; ++p) {
      int c = p * 256 + tid;
      int row = c >> 3, gc = (c & 7) ^ (row & 7);
      gload_lds16(Asrc + (size_t)row * K + t * 64 + gc * 8, As + (p * 256 + w * 64) * 8);
    }
  };
  auto compute = [&]() {
    bf16x8 af[MR][2];
#pragma unroll
    for (int i = 0; i < MR; ++i) {
      int m = w * MR * 16 + i * 16 + l15;
#pragma unroll
      for (int kk = 0; kk < 2; ++kk)
        af[i][kk] = *(const bf16x8*)((const char*)As + m * 128 + (((kk * 4 + g4) ^ (m & 7)) << 4));
    }
#pragma unroll
    for (int kk = 0; kk < 2; ++kk)
#pragma unroll
      for (int j = 0; j < 4; ++j) {
        int n = j * 16 + l15;
        union { unsigned u[4]; bf16x8 v; } fb;
#pragma unroll
        for (int d = 0; d < 4; ++d) {
          int kp = kk * 16 + g4 * 4 + d;
          fb.u[d] = Bp[kp * 64 + (((n >> 2) ^ (kp & 7)) << 2) + (n & 3)];
        }
#pragma unroll
        for (int i = 0; i < MR; ++i)
          acc[i][j] = __builtin_amdgcn_mfma_f32_16x16x32_bf16(af[i][kk], fb.v, acc[i][j], 0, 0, 0);
      }
  };

  // prologue: tile 0
  loadB(0, bregA);
  issueA(0);
  writeB(bregA);
  __syncthreads();
  loadB(1, bregB);           // B(1) flies under compute(0)
  compute();
  __syncthreads();

  // main: 2 tiles per iteration, breg sets alternate statically
  for (int t = 1; t + 1 < NT; t += 2) {
    // tile t (B in bregB)
    issueA(t);
    writeB(bregB);
    __syncthreads();
    loadB(t + 1, bregA);
    compute();
    __syncthreads();
    // tile t+1 (B in bregA)
    issueA(t + 1);
    writeB(bregA);
    __syncthreads();
    loadB(t + 2, bregB);
    compute();
    __syncthreads();
  }
  // tail: tile NT-1 (B in bregB, loaded in last iteration)
  issueA(NT - 1);
  writeB(bregB);
  __syncthreads();
  compute();

  // ---- epilogue ----
  if constexpr (MODE == 0) {
#pragma unroll
    for (int i = 0; i < MR; ++i)
#pragma unroll
      for (int j = 0; j < 4; ++j)
#pragma unroll
        for (int r = 0; r < 4; ++r) {
          size_t row = bm * MR * 64 + w * MR * 16 + i * 16 + g4 * 4 + r;
          size_t col = bn * 64 + j * 16 + l15;
          C[row * 4096 + col] = acc[i][j][r];
        }
  } else {
    if (bn < 80) {
      __bf16* dst = (bn < 64) ? Qb : Kb;
      int ldc = (bn < 64) ? 4096 : 1024;
#pragma unroll
      for (int i = 0; i < MR; ++i)
#pragma unroll
        for (int j = 0; j < 4; ++j)
#pragma unroll
          for (int r = 0; r < 4; ++r) {
            size_t row = bm * MR * 64 + w * MR * 16 + i * 16 + g4 * 4 + r;
            size_t col = (size_t)nloc + j * 16 + l15;
            dst[row * ldc + col] = (__bf16)acc[i][j][r];
          }
    } else {
      // V: write transposed -> Vt[n][s]
#pragma unroll
      for (int i = 0; i < MR; ++i)
#pragma unroll
        for (int j = 0; j < 4; ++j) {
          size_t n = (size_t)nloc + j * 16 + l15;
          size_t m0 = bm * MR * 64 + w * MR * 16 + i * 16 + g4 * 4;
          bf16x4 v;
          v.x = (__bf16)acc[i][j][0]; v.y = (__bf16)acc[i][j][1];
          v.z = (__bf16)acc[i][j][2]; v.w = (__bf16)acc[i][j][3];
          *(bf16x4*)&Vt[n * 1024 + m0] = v;
        }
    }
  }
}

// ---------------- flash attention (round-2 proven) ----------------
__global__ __launch_bounds__(256) void k_attn(const __bf16* __restrict__ Q,
                                              const __bf16* __restrict__ Kb,
                                              const __bf16* __restrict__ Vt,
                                              __bf16* __restrict__ ctx) {
  __shared__ __align__(16) char lds_raw[65536];
  __bf16* Ks = (__bf16*)lds_raw;
  __bf16* Vs = (__bf16*)(lds_raw + 32768);

  const int h = blockIdx.y, g = h >> 2;
  const int q0 = blockIdx.x * 64;
  const int tid = threadIdx.x, w = tid >> 6, l = tid & 63;
  const int l15 = l & 15, g4 = l >> 4;
  const float scale = 0.08838834764831845f;

  bf16x8 qf[4];
  const int qrow = q0 + w * 16 + l15;
#pragma unroll
  for (int ks = 0; ks < 4; ++ks)
    qf[ks] = *(const bf16x8*)&Q[(size_t)qrow * (NH * HD) + h * HD + ks * 32 + g4 * 8];

  f32x4 acc[8];
#pragma unroll
  for (int i = 0; i < 8; ++i)
#pragma unroll
    for (int r = 0; r < 4; ++r) acc[i][r] = 0.f;
  float m_run = -__builtin_inff(), l_run = 0.f;

  const int ntiles = (q0 + 64 + 127) >> 7;
  for (int kt = 0; kt < ntiles; ++kt) {
    const int kv0 = kt * 128;
#pragma unroll
    for (int p = 0; p < 8; ++p) {
      int c = p * 256 + tid;
      int row = c >> 4, cc = c & 15;
      gload_lds16(&Kb[(size_t)(kv0 + row) * (NG * HD) + g * HD + ((cc ^ (row & 7)) << 3)],
                  &Ks[(p * 256 + w * 64) * 8]);
      gload_lds16(&Vt[(size_t)(g * HD + row) * S_LEN + kv0 + ((cc ^ (row & 7)) << 3)],
                  &Vs[(p * 256 + w * 64) * 8]);
    }
    __syncthreads();

    float sreg[8][4];
    const bool need_mask = (kv0 + 127 > q0);
#pragma unroll
    for (int tf = 0; tf < 8; ++tf) {
      f32x4 sa;
#pragma unroll
      for (int r = 0; r < 4; ++r) sa[r] = 0.f;
      int t_loc = tf * 16 + l15;
#pragma unroll
      for (int ks = 0; ks < 4; ++ks) {
        bf16x8 kf = *(const bf16x8*)((const char*)Ks + t_loc * 256 + (((ks * 4 + g4) ^ (t_loc & 7)) << 4));
        sa = __builtin_amdgcn_mfma_f32_16x16x32_bf16(kf, qf[ks], sa, 0, 0, 0);
      }
#pragma unroll
      for (int r = 0; r < 4; ++r) {
        float v = sa[r] * scale;
        if (need_mask && (kv0 + tf * 16 + g4 * 4 + r) > qrow) v = -__builtin_inff();
        sreg[tf][r] = v;
      }
    }
    float mx = -__builtin_inff();
#pragma unroll
    for (int tf = 0; tf < 8; ++tf)
#pragma unroll
      for (int r = 0; r < 4; ++r) mx = fmaxf(mx, sreg[tf][r]);
    mx = fmaxf(mx, __shfl_xor(mx, 16));
    mx = fmaxf(mx, __shfl_xor(mx, 32));
    const float m_new = fmaxf(m_run, mx);
    const float alpha = __expf(m_run - m_new);
    float ssum = 0.f;
#pragma unroll
    for (int tf = 0; tf < 8; ++tf)
#pragma unroll
      for (int r = 0; r < 4; ++r) {
        sreg[tf][r] = __expf(sreg[tf][r] - m_new);
        ssum += sreg[tf][r];
      }
    ssum += __shfl_xor(ssum, 16);
    ssum += __shfl_xor(ssum, 32);
    l_run = l_run * alpha + ssum;
    m_run = m_new;
    float ar[4];
#pragma unroll
    for (int r = 0; r < 4; ++r) ar[r] = __shfl(alpha, g4 * 4 + r);
#pragma unroll
    for (int nf = 0; nf < 8; ++nf)
#pragma unroll
      for (int r = 0; r < 4; ++r) acc[nf][r] *= ar[r];

    __syncthreads();

    char* pb = lds_raw + w * 4096;
#pragma unroll
    for (int tf = 0; tf < 8; ++tf) {
      int chunkc = 2 * tf + (g4 >> 1);
      int addr = l15 * 256 + ((chunkc ^ (l15 & 7)) << 4) + ((g4 & 1) << 3);
      *(unsigned*)(pb + addr)     = pack2bf(sreg[tf][0], sreg[tf][1]);
      *(unsigned*)(pb + addr + 4) = pack2bf(sreg[tf][2], sreg[tf][3]);
    }
    asm volatile("s_waitcnt lgkmcnt(0)" ::: "memory");
    bf16x8 pf[4];
#pragma unroll
    for (int ks = 0; ks < 4; ++ks)
      pf[ks] = *(const bf16x8*)(pb + l15 * 256 + (((ks * 4 + g4) ^ (l15 & 7)) << 4));
#pragma unroll
    for (int nf = 0; nf < 8; ++nf) {
      int d_loc = nf * 16 + l15;
#pragma unroll
      for (int ks = 0; ks < 4; ++ks) {
        bf16x8 vf = *(const bf16x8*)((const char*)Vs + d_loc * 256 + (((ks * 4 + g4) ^ (d_loc & 7)) << 4));
        acc[nf] = __builtin_amdgcn_mfma_f32_16x16x32_bf16(pf[ks], vf, acc[nf], 0, 0, 0);
      }
    }
    __syncthreads();
  }
  float li[4];
#pragma unroll
  for (int r = 0; r < 4; ++r) li[r] = 1.f / __shfl(l_run, g4 * 4 + r);
#pragma unroll
  for (int nf = 0; nf < 8; ++nf)
#pragma unroll
    for (int r = 0; r < 4; ++r) {
      size_t row = q0 + w * 16 + g4 * 4 + r;
      size_t col = (size_t)h * HD + nf * 16 + l15;
      ctx[row * (NH * HD) + col] = (__bf16)(acc[nf][r] * li[r]);
    }
}

// ---------------- host ----------------
extern "C" void kernel_launch(void* const* d_in, const int* in_sizes, int n_in,
                              void* d_out, int out_size, void* d_ws, size_t ws_size,
                              hipStream_t stream) {
  const float* x    = (const float*)d_in[0];
  const float* cosT = (const float*)d_in[2];
  const float* sinT = (const float*)d_in[3];
  const float* Wq   = (const float*)d_in[4];
  const float* Wk   = (const float*)d_in[5];
  const float* Wv   = (const float*)d_in[6];
  const float* Wo   = (const float*)d_in[7];
  float* out = (float*)d_out;

  char* ws = (char*)d_ws;
  const size_t MB = 1u << 20;
  __bf16* xb   = (__bf16*)(ws + 0);        // 8 MB : x bf16; reused as ctx after QKV
  __bf16* Qb   = (__bf16*)(ws + 8 * MB);   // 8 MB : Q, roped in-place
  __bf16* Kbuf = (__bf16*)(ws + 16 * MB);  // 2 MB : K, roped in-place
  __bf16* Vtb  = (__bf16*)(ws + 18 * MB);  // 2 MB : V^T (direct from epilogue)
  __bf16* ctxb = (__bf16*)(ws + 0);        // aliases xb (dead after QKV GEMM)

  k_cast<<<4096, 256, 0, stream>>>(x, xb, (S_LEN * DIN) / 4);

  // fused QKV: f32 weights direct, BM=256, 4 blocks/CU. grid (96,4).
  k_gemm<1, 4><<<dim3(96, 4), 256, 0, stream>>>(xb, Wq, Wk, Wv, nullptr, Qb, Kbuf, Vtb);

  k_rope<<<2560, 256, 0, stream>>>(Qb, Kbuf, cosT, sinT);

  k_attn<<<dim3(16, 32), 256, 0, stream>>>(Qb, Kbuf, Vtb, ctxb);

  // out = ctx * Wo, f32 out, BM=256, 4 blocks/CU. grid (64,4).
  k_gemm<0, 4><<<dim3(64, 4), 256, 0, stream>>>(ctxb, Wo, nullptr, nullptr, out,
                                                nullptr, nullptr, nullptr);
}

// Round 18
// 222.939 us; speedup vs baseline: 4.9261x; 4.9261x over previous
//
#include <hip/hip_runtime.h>
#include <hip/hip_bf16.h>

#define S_LEN 1024
#define DIN 4096
#define NH 32
#define NG 8
#define HD 128

typedef __bf16 bf16x8 __attribute__((ext_vector_type(8)));
typedef __bf16 bf16x4 __attribute__((ext_vector_type(4)));
typedef float f32x4 __attribute__((ext_vector_type(4)));

__device__ __forceinline__ void gload_lds16(const void* g, void* l) {
  __builtin_amdgcn_global_load_lds(
      (const __attribute__((address_space(1))) unsigned int*)g,
      (__attribute__((address_space(3))) unsigned int*)l, 16, 0, 0);
}

__device__ __forceinline__ unsigned pack2bf(float a, float b) {
  union { __bf16 h[2]; unsigned u; } x;
  x.h[0] = (__bf16)a; x.h[1] = (__bf16)b;
  return x.u;
}

// ---------------- cast x: f32 -> bf16 (the only prep) ----------------
__global__ __launch_bounds__(256) void k_cast(const float* __restrict__ in,
                                              __bf16* __restrict__ out, int n4) {
  int i = blockIdx.x * 256 + threadIdx.x;
  if (i >= n4) return;
  const float4 v = ((const float4*)in)[i];
  bf16x4 o;
  o.x = (__bf16)v.x; o.y = (__bf16)v.y; o.z = (__bf16)v.z; o.w = (__bf16)v.w;
  ((bf16x4*)out)[i] = o;
}

// ---------------- RoPE, vectorized: 4 d-pairs per thread ----------------
__global__ __launch_bounds__(256) void k_rope(__bf16* __restrict__ Q, __bf16* __restrict__ Kb,
                                              const float* __restrict__ cosT,
                                              const float* __restrict__ sinT) {
  int idx = blockIdx.x * 256 + threadIdx.x;
  int d = (idx & 15) * 4;
  int row = idx >> 4;
  __bf16* p; int s;
  if (row < S_LEN * NH) { p = Q + (size_t)row * HD; s = row >> 5; }
  else { int r = row - S_LEN * NH; p = Kb + (size_t)r * HD; s = r >> 3; }
  const float4 c = *(const float4*)&cosT[s * HD + d];
  const float4 sn = *(const float4*)&sinT[s * HD + d];
  bf16x4 a = *(const bf16x4*)&p[d];
  bf16x4 b = *(const bf16x4*)&p[d + 64];
  bf16x4 oa, ob;
  oa.x = (__bf16)((float)a.x * c.x - (float)b.x * sn.x);
  oa.y = (__bf16)((float)a.y * c.y - (float)b.y * sn.y);
  oa.z = (__bf16)((float)a.z * c.z - (float)b.z * sn.z);
  oa.w = (__bf16)((float)a.w * c.w - (float)b.w * sn.w);
  ob.x = (__bf16)((float)b.x * c.x + (float)a.x * sn.x);
  ob.y = (__bf16)((float)b.y * c.y + (float)a.y * sn.y);
  ob.z = (__bf16)((float)b.z * c.z + (float)a.z * sn.z);
  ob.w = (__bf16)((float)b.w * c.w + (float)a.w * sn.w);
  *(bf16x4*)&p[d] = oa;
  *(bf16x4*)&p[d + 64] = ob;
}

// ---------------- GEMM: C(M,N) = A(M,K,bf16) * W(K,N,f32) ----------------
// BM=256, BN=64, BK=64. 4 waves, wave w owns rows [w*64,(w+1)*64).
// r17 post-mortem: launch_bounds(256,4) + MR=4 SPILLED (VGPR crushed to 64,
// 848MB scratch writes). VGPR audit: acc 64 + af 32 + breg 16 + temps ~25
// ~= 140 -> 3 blocks/CU max (cap ~170). This round: r2's proven
// single-buffer 2-barrier cadence + f32-reg-B + MR=4 at launch_bounds(256,3)
// (LDS 40KB -> 3 blocks/CU; TLP fills the barrier vmcnt(0) drain, as in r2).
// Single breg set: loadB(t+1) issues BEFORE compute(t); consumed by writeB
// after barrier1 -> one full compute phase of flight, no extra registers.
// B: k-pair packed dwords, b128 to Bp[kp][16c][4] at cphys=(nn>>2)^(kp&7)
//    [r10-PROVEN 0 conflicts]. Frag: 4 b32, 32 banks x 2-way (free).
// A: DMA-staged bf16, XOR chunk swizzle (proven 0-conflict).
// MODE 0: f32 C, grid (64,4). MODE 1: QKV split epilogue, grid (96,4).
template <int MODE>
__global__ __launch_bounds__(256, 3)
void k_gemm(const __bf16* __restrict__ A,
            const float* __restrict__ W0,
            const float* __restrict__ W1,
            const float* __restrict__ W2,
            float* __restrict__ C,
            __bf16* __restrict__ Qb,
            __bf16* __restrict__ Kb,
            __bf16* __restrict__ Vt) {
  __shared__ __bf16 As[256 * 64];       // 32 KB, single-buffered
  __shared__ unsigned Bp[32 * 64];      // 8 KB
  const int bm = blockIdx.y, bn = blockIdx.x;
  const int K = DIN, NT = K / 64;

  const float* Wsrc; int ldb, nloc;
  if (MODE == 0) { Wsrc = W0; ldb = 4096; nloc = bn * 64; }
  else {
    if (bn < 64)      { Wsrc = W0; ldb = 4096; nloc = bn * 64; }
    else if (bn < 80) { Wsrc = W1; ldb = 1024; nloc = (bn - 64) * 64; }
    else              { Wsrc = W2; ldb = 1024; nloc = (bn - 80) * 64; }
  }

  const int tid = threadIdx.x, w = tid >> 6;
  const int l = tid & 63, l15 = l & 15, g4 = l >> 4;

  const __bf16* Asrc = A + (size_t)(bm * 256) * K;

  f32x4 acc[4][4];
#pragma unroll
  for (int i = 0; i < 4; ++i)
#pragma unroll
    for (int j = 0; j < 4; ++j)
#pragma unroll
      for (int r = 0; r < 4; ++r) acc[i][j][r] = 0.f;

  // single B staging reg set (r2 cadence makes one set sufficient)
  float4 breg[2][2];
  const int kp_s[2] = {tid >> 4, 16 + (tid >> 4)};
  const int nn_s = (tid & 15) * 4;

  auto loadB = [&](int t) {
    if (t >= NT) return;
#pragma unroll
    for (int p = 0; p < 2; ++p) {
      const float* src = Wsrc + (size_t)(t * 64 + 2 * kp_s[p]) * ldb + nloc + nn_s;
      breg[p][0] = *(const float4*)src;
      breg[p][1] = *(const float4*)(src + ldb);
    }
  };
  auto writeB = [&]() {
#pragma unroll
    for (int p = 0; p < 2; ++p) {
      int kp = kp_s[p];
      int cphys = (nn_s >> 2) ^ (kp & 7);
      uint4 d;
      d.x = pack2bf(breg[p][0].x, breg[p][1].x);
      d.y = pack2bf(breg[p][0].y, breg[p][1].y);
      d.z = pack2bf(breg[p][0].z, breg[p][1].z);
      d.w = pack2bf(breg[p][0].w, breg[p][1].w);
      *(uint4*)&Bp[kp * 64 + cphys * 4] = d;
    }
  };
  auto issueA = [&](int t) {
#pragma unroll
    for (int p = 0; p < 8; ++p) {
      int c = p * 256 + tid;
      int row = c >> 3, gc = (c & 7) ^ (row & 7);
      gload_lds16(Asrc + (size_t)row * K + t * 64 + gc * 8, As + (p * 256 + w * 64) * 8);
    }
  };
  auto compute = [&]() {
    bf16x8 af[4][2];
#pragma unroll
    for (int i = 0; i < 4; ++i) {
      int m = w * 64 + i * 16 + l15;
#pragma unroll
      for (int kk = 0; kk < 2; ++kk)
        af[i][kk] = *(const bf16x8*)((const char*)As + m * 128 + (((kk * 4 + g4) ^ (m & 7)) << 4));
    }
#pragma unroll
    for (int kk = 0; kk < 2; ++kk)
#pragma unroll
      for (int j = 0; j < 4; ++j) {
        int n = j * 16 + l15;
        union { unsigned u[4]; bf16x8 v; } fb;
#pragma unroll
        for (int d = 0; d < 4; ++d) {
          int kp = kk * 16 + g4 * 4 + d;
          fb.u[d] = Bp[kp * 64 + (((n >> 2) ^ (kp & 7)) << 2) + (n & 3)];
        }
#pragma unroll
        for (int i = 0; i < 4; ++i)
          acc[i][j] = __builtin_amdgcn_mfma_f32_16x16x32_bf16(af[i][kk], fb.v, acc[i][j], 0, 0, 0);
      }
  };

  // prologue: stage tile 0
  loadB(0);
  issueA(0);
  writeB();            // compiler inserts vmcnt for breg deps
  __syncthreads();     // drains A DMA + ds_writes

  for (int t = 0; t < NT; ++t) {
    loadB(t + 1);      // regs only; ~1 compute phase of flight
    compute();         // reads As(t), Bp(t)
    __syncthreads();   // all waves done reading
    if (t + 1 < NT) {
      issueA(t + 1);   // overwrite As
      writeB();        // overwrite Bp (breg landed during compute)
      __syncthreads(); // staging visible; vmcnt(0) drain filled by 3-blk TLP
    }
  }

  // ---- epilogue ----
  if constexpr (MODE == 0) {
#pragma unroll
    for (int i = 0; i < 4; ++i)
#pragma unroll
      for (int j = 0; j < 4; ++j)
#pragma unroll
        for (int r = 0; r < 4; ++r) {
          size_t row = bm * 256 + w * 64 + i * 16 + g4 * 4 + r;
          size_t col = bn * 64 + j * 16 + l15;
          C[row * 4096 + col] = acc[i][j][r];
        }
  } else {
    if (bn < 80) {
      __bf16* dst = (bn < 64) ? Qb : Kb;
      int ldc = (bn < 64) ? 4096 : 1024;
#pragma unroll
      for (int i = 0; i < 4; ++i)
#pragma unroll
        for (int j = 0; j < 4; ++j)
#pragma unroll
          for (int r = 0; r < 4; ++r) {
            size_t row = bm * 256 + w * 64 + i * 16 + g4 * 4 + r;
            size_t col = (size_t)nloc + j * 16 + l15;
            dst[row * ldc + col] = (__bf16)acc[i][j][r];
          }
    } else {
      // V: write transposed -> Vt[n][s]
#pragma unroll
      for (int i = 0; i < 4; ++i)
#pragma unroll
        for (int j = 0; j < 4; ++j) {
          size_t n = (size_t)nloc + j * 16 + l15;
          size_t m0 = bm * 256 + w * 64 + i * 16 + g4 * 4;
          bf16x4 v;
          v.x = (__bf16)acc[i][j][0]; v.y = (__bf16)acc[i][j][1];
          v.z = (__bf16)acc[i][j][2]; v.w = (__bf16)acc[i][j][3];
          *(bf16x4*)&Vt[n * 1024 + m0] = v;
        }
    }
  }
}

// ---------------- flash attention (round-2 proven) ----------------
__global__ __launch_bounds__(256) void k_attn(const __bf16* __restrict__ Q,
                                              const __bf16* __restrict__ Kb,
                                              const __bf16* __restrict__ Vt,
                                              __bf16* __restrict__ ctx) {
  __shared__ __align__(16) char lds_raw[65536];
  __bf16* Ks = (__bf16*)lds_raw;
  __bf16* Vs = (__bf16*)(lds_raw + 32768);

  const int h = blockIdx.y, g = h >> 2;
  const int q0 = blockIdx.x * 64;
  const int tid = threadIdx.x, w = tid >> 6, l = tid & 63;
  const int l15 = l & 15, g4 = l >> 4;
  const float scale = 0.08838834764831845f;

  bf16x8 qf[4];
  const int qrow = q0 + w * 16 + l15;
#pragma unroll
  for (int ks = 0; ks < 4; ++ks)
    qf[ks] = *(const bf16x8*)&Q[(size_t)qrow * (NH * HD) + h * HD + ks * 32 + g4 * 8];

  f32x4 acc[8];
#pragma unroll
  for (int i = 0; i < 8; ++i)
#pragma unroll
    for (int r = 0; r < 4; ++r) acc[i][r] = 0.f;
  float m_run = -__builtin_inff(), l_run = 0.f;

  const int ntiles = (q0 + 64 + 127) >> 7;
  for (int kt = 0; kt < ntiles; ++kt) {
    const int kv0 = kt * 128;
#pragma unroll
    for (int p = 0; p < 8; ++p) {
      int c = p * 256 + tid;
      int row = c >> 4, cc = c & 15;
      gload_lds16(&Kb[(size_t)(kv0 + row) * (NG * HD) + g * HD + ((cc ^ (row & 7)) << 3)],
                  &Ks[(p * 256 + w * 64) * 8]);
      gload_lds16(&Vt[(size_t)(g * HD + row) * S_LEN + kv0 + ((cc ^ (row & 7)) << 3)],
                  &Vs[(p * 256 + w * 64) * 8]);
    }
    __syncthreads();

    float sreg[8][4];
    const bool need_mask = (kv0 + 127 > q0);
#pragma unroll
    for (int tf = 0; tf < 8; ++tf) {
      f32x4 sa;
#pragma unroll
      for (int r = 0; r < 4; ++r) sa[r] = 0.f;
      int t_loc = tf * 16 + l15;
#pragma unroll
      for (int ks = 0; ks < 4; ++ks) {
        bf16x8 kf = *(const bf16x8*)((const char*)Ks + t_loc * 256 + (((ks * 4 + g4) ^ (t_loc & 7)) << 4));
        sa = __builtin_amdgcn_mfma_f32_16x16x32_bf16(kf, qf[ks], sa, 0, 0, 0);
      }
#pragma unroll
      for (int r = 0; r < 4; ++r) {
        float v = sa[r] * scale;
        if (need_mask && (kv0 + tf * 16 + g4 * 4 + r) > qrow) v = -__builtin_inff();
        sreg[tf][r] = v;
      }
    }
    float mx = -__builtin_inff();
#pragma unroll
    for (int tf = 0; tf < 8; ++tf)
#pragma unroll
      for (int r = 0; r < 4; ++r) mx = fmaxf(mx, sreg[tf][r]);
    mx = fmaxf(mx, __shfl_xor(mx, 16));
    mx = fmaxf(mx, __shfl_xor(mx, 32));
    const float m_new = fmaxf(m_run, mx);
    const float alpha = __expf(m_run - m_new);
    float ssum = 0.f;
#pragma unroll
    for (int tf = 0; tf < 8; ++tf)
#pragma unroll
      for (int r = 0; r < 4; ++r) {
        sreg[tf][r] = __expf(sreg[tf][r] - m_new);
        ssum += sreg[tf][r];
      }
    ssum += __shfl_xor(ssum, 16);
    ssum += __shfl_xor(ssum, 32);
    l_run = l_run * alpha + ssum;
    m_run = m_new;
    float ar[4];
#pragma unroll
    for (int r = 0; r < 4; ++r) ar[r] = __shfl(alpha, g4 * 4 + r);
#pragma unroll
    for (int nf = 0; nf < 8; ++nf)
#pragma unroll
      for (int r = 0; r < 4; ++r) acc[nf][r] *= ar[r];

    __syncthreads();

    char* pb = lds_raw + w * 4096;
#pragma unroll
    for (int tf = 0; tf < 8; ++tf) {
      int chunkc = 2 * tf + (g4 >> 1);
      int addr = l15 * 256 + ((chunkc ^ (l15 & 7)) << 4) + ((g4 & 1) << 3);
      *(unsigned*)(pb + addr)     = pack2bf(sreg[tf][0], sreg[tf][1]);
      *(unsigned*)(pb + addr + 4) = pack2bf(sreg[tf][2], sreg[tf][3]);
    }
    asm volatile("s_waitcnt lgkmcnt(0)" ::: "memory");
    bf16x8 pf[4];
#pragma unroll
    for (int ks = 0; ks < 4; ++ks)
      pf[ks] = *(const bf16x8*)(pb + l15 * 256 + (((ks * 4 + g4) ^ (l15 & 7)) << 4));
#pragma unroll
    for (int nf = 0; nf < 8; ++nf) {
      int d_loc = nf * 16 + l15;
#pragma unroll
      for (int ks = 0; ks < 4; ++ks) {
        bf16x8 vf = *(const bf16x8*)((const char*)Vs + d_loc * 256 + (((ks * 4 + g4) ^ (d_loc & 7)) << 4));
        acc[nf] = __builtin_amdgcn_mfma_f32_16x16x32_bf16(pf[ks], vf, acc[nf], 0, 0, 0);
      }
    }
    __syncthreads();
  }
  float li[4];
#pragma unroll
  for (int r = 0; r < 4; ++r) li[r] = 1.f / __shfl(l_run, g4 * 4 + r);
#pragma unroll
  for (int nf = 0; nf < 8; ++nf)
#pragma unroll
    for (int r = 0; r < 4; ++r) {
      size_t row = q0 + w * 16 + g4 * 4 + r;
      size_t col = (size_t)h * HD + nf * 16 + l15;
      ctx[row * (NH * HD) + col] = (__bf16)(acc[nf][r] * li[r]);
    }
}

// ---------------- host ----------------
extern "C" void kernel_launch(void* const* d_in, const int* in_sizes, int n_in,
                              void* d_out, int out_size, void* d_ws, size_t ws_size,
                              hipStream_t stream) {
  const float* x    = (const float*)d_in[0];
  const float* cosT = (const float*)d_in[2];
  const float* sinT = (const float*)d_in[3];
  const float* Wq   = (const float*)d_in[4];
  const float* Wk   = (const float*)d_in[5];
  const float* Wv   = (const float*)d_in[6];
  const float* Wo   = (const float*)d_in[7];
  float* out = (float*)d_out;

  char* ws = (char*)d_ws;
  const size_t MB = 1u << 20;
  __bf16* xb   = (__bf16*)(ws + 0);        // 8 MB : x bf16; reused as ctx after QKV
  __bf16* Qb   = (__bf16*)(ws + 8 * MB);   // 8 MB : Q, roped in-place
  __bf16* Kbuf = (__bf16*)(ws + 16 * MB);  // 2 MB : K, roped in-place
  __bf16* Vtb  = (__bf16*)(ws + 18 * MB);  // 2 MB : V^T (direct from epilogue)
  __bf16* ctxb = (__bf16*)(ws + 0);        // aliases xb (dead after QKV GEMM)

  k_cast<<<4096, 256, 0, stream>>>(x, xb, (S_LEN * DIN) / 4);

  // fused QKV: f32 weights direct, BM=256, 3 blocks/CU. grid (96,4).
  k_gemm<1><<<dim3(96, 4), 256, 0, stream>>>(xb, Wq, Wk, Wv, nullptr, Qb, Kbuf, Vtb);

  k_rope<<<2560, 256, 0, stream>>>(Qb, Kbuf, cosT, sinT);

  k_attn<<<dim3(16, 32), 256, 0, stream>>>(Qb, Kbuf, Vtb, ctxb);

  // out = ctx * Wo, f32 out, BM=256, 3 blocks/CU. grid (64,4).
  k_gemm<0><<<dim3(64, 4), 256, 0, stream>>>(ctxb, Wo, nullptr, nullptr, out,
                                             nullptr, nullptr, nullptr);
}

// Round 19
// 201.116 us; speedup vs baseline: 5.4606x; 1.1085x over previous
//
#include <hip/hip_runtime.h>
#include <hip/hip_bf16.h>

#define S_LEN 1024
#define DIN 4096
#define NH 32
#define NG 8
#define HD 128

typedef __bf16 bf16x8 __attribute__((ext_vector_type(8)));
typedef __bf16 bf16x4 __attribute__((ext_vector_type(4)));
typedef float f32x4 __attribute__((ext_vector_type(4)));

__device__ __forceinline__ void gload_lds16(const void* g, void* l) {
  __builtin_amdgcn_global_load_lds(
      (const __attribute__((address_space(1))) unsigned int*)g,
      (__attribute__((address_space(3))) unsigned int*)l, 16, 0, 0);
}

__device__ __forceinline__ unsigned pack2bf(float a, float b) {
  union { __bf16 h[2]; unsigned u; } x;
  x.h[0] = (__bf16)a; x.h[1] = (__bf16)b;
  return x.u;
}

// ---------------- cast x: f32 -> bf16 (the only prep) ----------------
__global__ __launch_bounds__(256) void k_cast(const float* __restrict__ in,
                                              __bf16* __restrict__ out, int n4) {
  int i = blockIdx.x * 256 + threadIdx.x;
  if (i >= n4) return;
  const float4 v = ((const float4*)in)[i];
  bf16x4 o;
  o.x = (__bf16)v.x; o.y = (__bf16)v.y; o.z = (__bf16)v.z; o.w = (__bf16)v.w;
  ((bf16x4*)out)[i] = o;
}

// ---------------- RoPE, vectorized: 4 d-pairs per thread ----------------
__global__ __launch_bounds__(256) void k_rope(__bf16* __restrict__ Q, __bf16* __restrict__ Kb,
                                              const float* __restrict__ cosT,
                                              const float* __restrict__ sinT) {
  int idx = blockIdx.x * 256 + threadIdx.x;
  int d = (idx & 15) * 4;
  int row = idx >> 4;
  __bf16* p; int s;
  if (row < S_LEN * NH) { p = Q + (size_t)row * HD; s = row >> 5; }
  else { int r = row - S_LEN * NH; p = Kb + (size_t)r * HD; s = r >> 3; }
  const float4 c = *(const float4*)&cosT[s * HD + d];
  const float4 sn = *(const float4*)&sinT[s * HD + d];
  bf16x4 a = *(const bf16x4*)&p[d];
  bf16x4 b = *(const bf16x4*)&p[d + 64];
  bf16x4 oa, ob;
  oa.x = (__bf16)((float)a.x * c.x - (float)b.x * sn.x);
  oa.y = (__bf16)((float)a.y * c.y - (float)b.y * sn.y);
  oa.z = (__bf16)((float)a.z * c.z - (float)b.z * sn.z);
  oa.w = (__bf16)((float)a.w * c.w - (float)b.w * sn.w);
  ob.x = (__bf16)((float)b.x * c.x + (float)a.x * sn.x);
  ob.y = (__bf16)((float)b.y * c.y + (float)a.y * sn.y);
  ob.z = (__bf16)((float)b.z * c.z + (float)a.z * sn.z);
  ob.w = (__bf16)((float)b.w * c.w + (float)a.w * sn.w);
  *(bf16x4*)&p[d] = oa;
  *(bf16x4*)&p[d + 64] = ob;
}

// ---------------- GEMM: C(M,N) = A(M,K,bf16) * W(K,N,f32) ----------------
// BM = MR*64, BN=64, BK=64. 4 waves, wave w owns rows [w*MR*16, (w+1)*MR*16).
// r14 checkpoint (session best, 196.4us): double-buffered LDS, 3-stage B
// prefetch (2 named breg sets, loadB(t+2) ~2 k-steps before its writeB),
// plain __syncthreads (r15/r18 proved hand-sync and single-buffer regress).
// B: reg-staged f32, k-pair packed, b128 to Bp[kp][16c][4] at
//    cphys=(nn>>2)^(kp&7) [r10-PROVEN 0 conflicts]. Frag: 4 b32, 2-way free.
// A: DMA-staged bf16, XOR chunk swizzle (proven 0-conflict).
// MODE 0 (MR=2): f32 C, grid (64,8), 48KB LDS -> 3 blocks/CU.
// MODE 1 (MR=4): QKV split, grid (96,4), 80KB LDS -> 2 blocks/CU.
template <int MODE, int MR>
__global__ __launch_bounds__(256, (MR == 2) ? 3 : 2)
void k_gemm(const __bf16* __restrict__ A,
            const float* __restrict__ W0,
            const float* __restrict__ W1,
            const float* __restrict__ W2,
            float* __restrict__ C,
            __bf16* __restrict__ Qb,
            __bf16* __restrict__ Kb,
            __bf16* __restrict__ Vt) {
  __shared__ __bf16 As[2][MR * 64 * 64];
  __shared__ unsigned Bp[2][32 * 64];
  const int bm = blockIdx.y, bn = blockIdx.x;
  const int K = DIN, NT = K / 64;

  const float* Wsrc; int ldb, nloc;
  if (MODE == 0) { Wsrc = W0; ldb = 4096; nloc = bn * 64; }
  else {
    if (bn < 64)      { Wsrc = W0; ldb = 4096; nloc = bn * 64; }
    else if (bn < 80) { Wsrc = W1; ldb = 1024; nloc = (bn - 64) * 64; }
    else              { Wsrc = W2; ldb = 1024; nloc = (bn - 80) * 64; }
  }

  const int tid = threadIdx.x, w = tid >> 6;
  const int l = tid & 63, l15 = l & 15, g4 = l >> 4;

  const __bf16* Asrc = A + (size_t)(bm * MR * 64) * K;

  f32x4 acc[MR][4];
#pragma unroll
  for (int i = 0; i < MR; ++i)
#pragma unroll
    for (int j = 0; j < 4; ++j)
#pragma unroll
      for (int r = 0; r < 4; ++r) acc[i][j][r] = 0.f;

  // B staging: TWO named reg sets (3-stage pipeline; rule-#20 static indexing)
  float4 bregA[2][2], bregB[2][2];
  const int kp_s[2] = {tid >> 4, 16 + (tid >> 4)};
  const int nn_s = (tid & 15) * 4;

  auto loadB = [&](int t, float4 (&br)[2][2]) {
    if (t >= NT) return;
#pragma unroll
    for (int p = 0; p < 2; ++p) {
      const float* src = Wsrc + (size_t)(t * 64 + 2 * kp_s[p]) * ldb + nloc + nn_s;
      br[p][0] = *(const float4*)src;
      br[p][1] = *(const float4*)(src + ldb);
    }
  };
  auto writeB = [&](float4 (&br)[2][2], unsigned* dst) {
#pragma unroll
    for (int p = 0; p < 2; ++p) {
      int kp = kp_s[p];
      int cphys = (nn_s >> 2) ^ (kp & 7);
      uint4 d;
      d.x = pack2bf(br[p][0].x, br[p][1].x);
      d.y = pack2bf(br[p][0].y, br[p][1].y);
      d.z = pack2bf(br[p][0].z, br[p][1].z);
      d.w = pack2bf(br[p][0].w, br[p][1].w);
      *(uint4*)&dst[kp * 64 + cphys * 4] = d;
    }
  };
  auto issueA = [&](int t, __bf16* dst) {
#pragma unroll
    for (int p = 0; p < MR * 2; ++p) {
      int c = p * 256 + tid;
      int row = c >> 3, gc = (c & 7) ^ (row & 7);
      gload_lds16(Asrc + (size_t)row * K + t * 64 + gc * 8, dst + (p * 256 + w * 64) * 8);
    }
  };
  auto compute = [&](const __bf16* Ab, const unsigned* Bp_) {
    bf16x8 af[MR][2];
#pragma unroll
    for (int i = 0; i < MR; ++i) {
      int m = w * MR * 16 + i * 16 + l15;
#pragma unroll
      for (int kk = 0; kk < 2; ++kk)
        af[i][kk] = *(const bf16x8*)((const char*)Ab + m * 128 + (((kk * 4 + g4) ^ (m & 7)) << 4));
    }
#pragma unroll
    for (int kk = 0; kk < 2; ++kk)
#pragma unroll
      for (int j = 0; j < 4; ++j) {
        int n = j * 16 + l15;
        union { unsigned u[4]; bf16x8 v; } fb;
#pragma unroll
        for (int d = 0; d < 4; ++d) {
          int kp = kk * 16 + g4 * 4 + d;
          fb.u[d] = Bp_[kp * 64 + (((n >> 2) ^ (kp & 7)) << 2) + (n & 3)];
        }
#pragma unroll
        for (int i = 0; i < MR; ++i)
          acc[i][j] = __builtin_amdgcn_mfma_f32_16x16x32_bf16(af[i][kk], fb.v, acc[i][j], 0, 0, 0);
      }
  };

  // prologue: B loads for tiles 0 and 1 in flight; tile 0 staged
  loadB(0, bregA);
  loadB(1, bregB);
  issueA(0, As[0]);
  writeB(bregA, Bp[0]);     // compiler inserts the vmcnt wait for breg deps
  __syncthreads();          // drains A DMA + ds_writes

  for (int t = 0; t < NT; t += 2) {
    // --- half 1: compute tile t; stage t+1; launch B loads for t+2 ---
    loadB(t + 2, bregA);    // oldest issue: ~2 k-steps before its writeB
    issueA(t + 1, As[1]);
    compute(As[0], Bp[0]);
    writeB(bregB, Bp[1]);   // tile t+1 (loaded ~2 steps ago -> landed)
    __syncthreads();
    // --- half 2: compute tile t+1; stage t+2; launch B loads for t+3 ---
    loadB(t + 3, bregB);
    if (t + 2 < NT) issueA(t + 2, As[0]);
    compute(As[1], Bp[1]);
    if (t + 2 < NT) writeB(bregA, Bp[0]);  // tile t+2
    __syncthreads();
  }

  // ---- epilogue ----
  if constexpr (MODE == 0) {
#pragma unroll
    for (int i = 0; i < MR; ++i)
#pragma unroll
      for (int j = 0; j < 4; ++j)
#pragma unroll
        for (int r = 0; r < 4; ++r) {
          size_t row = bm * MR * 64 + w * MR * 16 + i * 16 + g4 * 4 + r;
          size_t col = bn * 64 + j * 16 + l15;
          C[row * 4096 + col] = acc[i][j][r];
        }
  } else {
    if (bn < 80) {
      __bf16* dst = (bn < 64) ? Qb : Kb;
      int ldc = (bn < 64) ? 4096 : 1024;
#pragma unroll
      for (int i = 0; i < MR; ++i)
#pragma unroll
        for (int j = 0; j < 4; ++j)
#pragma unroll
          for (int r = 0; r < 4; ++r) {
            size_t row = bm * MR * 64 + w * MR * 16 + i * 16 + g4 * 4 + r;
            size_t col = (size_t)nloc + j * 16 + l15;
            dst[row * ldc + col] = (__bf16)acc[i][j][r];
          }
    } else {
      // V: write transposed -> Vt[n][s]
#pragma unroll
      for (int i = 0; i < MR; ++i)
#pragma unroll
        for (int j = 0; j < 4; ++j) {
          size_t n = (size_t)nloc + j * 16 + l15;
          size_t m0 = bm * MR * 64 + w * MR * 16 + i * 16 + g4 * 4;
          bf16x4 v;
          v.x = (__bf16)acc[i][j][0]; v.y = (__bf16)acc[i][j][1];
          v.z = (__bf16)acc[i][j][2]; v.w = (__bf16)acc[i][j][3];
          *(bf16x4*)&Vt[n * 1024 + m0] = v;
        }
    }
  }
}

// ---------------- flash attention (round-2 proven) ----------------
__global__ __launch_bounds__(256) void k_attn(const __bf16* __restrict__ Q,
                                              const __bf16* __restrict__ Kb,
                                              const __bf16* __restrict__ Vt,
                                              __bf16* __restrict__ ctx) {
  __shared__ __align__(16) char lds_raw[65536];
  __bf16* Ks = (__bf16*)lds_raw;
  __bf16* Vs = (__bf16*)(lds_raw + 32768);

  const int h = blockIdx.y, g = h >> 2;
  const int q0 = blockIdx.x * 64;
  const int tid = threadIdx.x, w = tid >> 6, l = tid & 63;
  const int l15 = l & 15, g4 = l >> 4;
  const float scale = 0.08838834764831845f;

  bf16x8 qf[4];
  const int qrow = q0 + w * 16 + l15;
#pragma unroll
  for (int ks = 0; ks < 4; ++ks)
    qf[ks] = *(const bf16x8*)&Q[(size_t)qrow * (NH * HD) + h * HD + ks * 32 + g4 * 8];

  f32x4 acc[8];
#pragma unroll
  for (int i = 0; i < 8; ++i)
#pragma unroll
    for (int r = 0; r < 4; ++r) acc[i][r] = 0.f;
  float m_run = -__builtin_inff(), l_run = 0.f;

  const int ntiles = (q0 + 64 + 127) >> 7;
  for (int kt = 0; kt < ntiles; ++kt) {
    const int kv0 = kt * 128;
#pragma unroll
    for (int p = 0; p < 8; ++p) {
      int c = p * 256 + tid;
      int row = c >> 4, cc = c & 15;
      gload_lds16(&Kb[(size_t)(kv0 + row) * (NG * HD) + g * HD + ((cc ^ (row & 7)) << 3)],
                  &Ks[(p * 256 + w * 64) * 8]);
      gload_lds16(&Vt[(size_t)(g * HD + row) * S_LEN + kv0 + ((cc ^ (row & 7)) << 3)],
                  &Vs[(p * 256 + w * 64) * 8]);
    }
    __syncthreads();

    float sreg[8][4];
    const bool need_mask = (kv0 + 127 > q0);
#pragma unroll
    for (int tf = 0; tf < 8; ++tf) {
      f32x4 sa;
#pragma unroll
      for (int r = 0; r < 4; ++r) sa[r] = 0.f;
      int t_loc = tf * 16 + l15;
#pragma unroll
      for (int ks = 0; ks < 4; ++ks) {
        bf16x8 kf = *(const bf16x8*)((const char*)Ks + t_loc * 256 + (((ks * 4 + g4) ^ (t_loc & 7)) << 4));
        sa = __builtin_amdgcn_mfma_f32_16x16x32_bf16(kf, qf[ks], sa, 0, 0, 0);
      }
#pragma unroll
      for (int r = 0; r < 4; ++r) {
        float v = sa[r] * scale;
        if (need_mask && (kv0 + tf * 16 + g4 * 4 + r) > qrow) v = -__builtin_inff();
        sreg[tf][r] = v;
      }
    }
    float mx = -__builtin_inff();
#pragma unroll
    for (int tf = 0; tf < 8; ++tf)
#pragma unroll
      for (int r = 0; r < 4; ++r) mx = fmaxf(mx, sreg[tf][r]);
    mx = fmaxf(mx, __shfl_xor(mx, 16));
    mx = fmaxf(mx, __shfl_xor(mx, 32));
    const float m_new = fmaxf(m_run, mx);
    const float alpha = __expf(m_run - m_new);
    float ssum = 0.f;
#pragma unroll
    for (int tf = 0; tf < 8; ++tf)
#pragma unroll
      for (int r = 0; r < 4; ++r) {
        sreg[tf][r] = __expf(sreg[tf][r] - m_new);
        ssum += sreg[tf][r];
      }
    ssum += __shfl_xor(ssum, 16);
    ssum += __shfl_xor(ssum, 32);
    l_run = l_run * alpha + ssum;
    m_run = m_new;
    float ar[4];
#pragma unroll
    for (int r = 0; r < 4; ++r) ar[r] = __shfl(alpha, g4 * 4 + r);
#pragma unroll
    for (int nf = 0; nf < 8; ++nf)
#pragma unroll
      for (int r = 0; r < 4; ++r) acc[nf][r] *= ar[r];

    __syncthreads();

    char* pb = lds_raw + w * 4096;
#pragma unroll
    for (int tf = 0; tf < 8; ++tf) {
      int chunkc = 2 * tf + (g4 >> 1);
      int addr = l15 * 256 + ((chunkc ^ (l15 & 7)) << 4) + ((g4 & 1) << 3);
      *(unsigned*)(pb + addr)     = pack2bf(sreg[tf][0], sreg[tf][1]);
      *(unsigned*)(pb + addr + 4) = pack2bf(sreg[tf][2], sreg[tf][3]);
    }
    asm volatile("s_waitcnt lgkmcnt(0)" ::: "memory");
    bf16x8 pf[4];
#pragma unroll
    for (int ks = 0; ks < 4; ++ks)
      pf[ks] = *(const bf16x8*)(pb + l15 * 256 + (((ks * 4 + g4) ^ (l15 & 7)) << 4));
#pragma unroll
    for (int nf = 0; nf < 8; ++nf) {
      int d_loc = nf * 16 + l15;
#pragma unroll
      for (int ks = 0; ks < 4; ++ks) {
        bf16x8 vf = *(const bf16x8*)((const char*)Vs + d_loc * 256 + (((ks * 4 + g4) ^ (d_loc & 7)) << 4));
        acc[nf] = __builtin_amdgcn_mfma_f32_16x16x32_bf16(pf[ks], vf, acc[nf], 0, 0, 0);
      }
    }
    __syncthreads();
  }
  float li[4];
#pragma unroll
  for (int r = 0; r < 4; ++r) li[r] = 1.f / __shfl(l_run, g4 * 4 + r);
#pragma unroll
  for (int nf = 0; nf < 8; ++nf)
#pragma unroll
    for (int r = 0; r < 4; ++r) {
      size_t row = q0 + w * 16 + g4 * 4 + r;
      size_t col = (size_t)h * HD + nf * 16 + l15;
      ctx[row * (NH * HD) + col] = (__bf16)(acc[nf][r] * li[r]);
    }
}

// ---------------- host ----------------
extern "C" void kernel_launch(void* const* d_in, const int* in_sizes, int n_in,
                              void* d_out, int out_size, void* d_ws, size_t ws_size,
                              hipStream_t stream) {
  const float* x    = (const float*)d_in[0];
  const float* cosT = (const float*)d_in[2];
  const float* sinT = (const float*)d_in[3];
  const float* Wq   = (const float*)d_in[4];
  const float* Wk   = (const float*)d_in[5];
  const float* Wv   = (const float*)d_in[6];
  const float* Wo   = (const float*)d_in[7];
  float* out = (float*)d_out;

  char* ws = (char*)d_ws;
  const size_t MB = 1u << 20;
  __bf16* xb   = (__bf16*)(ws + 0);        // 8 MB : x bf16; reused as ctx after QKV
  __bf16* Qb   = (__bf16*)(ws + 8 * MB);   // 8 MB : Q, roped in-place
  __bf16* Kbuf = (__bf16*)(ws + 16 * MB);  // 2 MB : K, roped in-place
  __bf16* Vtb  = (__bf16*)(ws + 18 * MB);  // 2 MB : V^T (direct from epilogue)
  __bf16* ctxb = (__bf16*)(ws + 0);        // aliases xb (dead after QKV GEMM)

  k_cast<<<4096, 256, 0, stream>>>(x, xb, (S_LEN * DIN) / 4);

  // fused QKV: f32 weights direct, BM=256, 3-stage B prefetch. grid (96,4).
  k_gemm<1, 4><<<dim3(96, 4), 256, 0, stream>>>(xb, Wq, Wk, Wv, nullptr, Qb, Kbuf, Vtb);

  k_rope<<<2560, 256, 0, stream>>>(Qb, Kbuf, cosT, sinT);

  k_attn<<<dim3(16, 32), 256, 0, stream>>>(Qb, Kbuf, Vtb, ctxb);

  // out = ctx * Wo, f32 out, BM=128 (3 blocks/CU). grid (64,8).
  k_gemm<0, 2><<<dim3(64, 8), 256, 0, stream>>>(ctxb, Wo, nullptr, nullptr, out,
                                                nullptr, nullptr, nullptr);
}

// Round 20
// 197.326 us; speedup vs baseline: 5.5655x; 1.0192x over previous
//
#include <hip/hip_runtime.h>
#include <hip/hip_bf16.h>

#define S_LEN 1024
#define DIN 4096
#define NH 32
#define NG 8
#define HD 128

typedef __bf16 bf16x8 __attribute__((ext_vector_type(8)));
typedef __bf16 bf16x4 __attribute__((ext_vector_type(4)));
typedef float f32x4 __attribute__((ext_vector_type(4)));

__device__ __forceinline__ void gload_lds16(const void* g, void* l) {
  __builtin_amdgcn_global_load_lds(
      (const __attribute__((address_space(1))) unsigned int*)g,
      (__attribute__((address_space(3))) unsigned int*)l, 16, 0, 0);
}

__device__ __forceinline__ unsigned pack2bf(float a, float b) {
  union { __bf16 h[2]; unsigned u; } x;
  x.h[0] = (__bf16)a; x.h[1] = (__bf16)b;
  return x.u;
}

// ---------------- cast x: f32 -> bf16 (the only prep) ----------------
__global__ __launch_bounds__(256) void k_cast(const float* __restrict__ in,
                                              __bf16* __restrict__ out, int n4) {
  int i = blockIdx.x * 256 + threadIdx.x;
  if (i >= n4) return;
  const float4 v = ((const float4*)in)[i];
  bf16x4 o;
  o.x = (__bf16)v.x; o.y = (__bf16)v.y; o.z = (__bf16)v.z; o.w = (__bf16)v.w;
  ((bf16x4*)out)[i] = o;
}

// ---------------- RoPE, vectorized: 4 d-pairs per thread ----------------
__global__ __launch_bounds__(256) void k_rope(__bf16* __restrict__ Q, __bf16* __restrict__ Kb,
                                              const float* __restrict__ cosT,
                                              const float* __restrict__ sinT) {
  int idx = blockIdx.x * 256 + threadIdx.x;
  int d = (idx & 15) * 4;
  int row = idx >> 4;
  __bf16* p; int s;
  if (row < S_LEN * NH) { p = Q + (size_t)row * HD; s = row >> 5; }
  else { int r = row - S_LEN * NH; p = Kb + (size_t)r * HD; s = r >> 3; }
  const float4 c = *(const float4*)&cosT[s * HD + d];
  const float4 sn = *(const float4*)&sinT[s * HD + d];
  bf16x4 a = *(const bf16x4*)&p[d];
  bf16x4 b = *(const bf16x4*)&p[d + 64];
  bf16x4 oa, ob;
  oa.x = (__bf16)((float)a.x * c.x - (float)b.x * sn.x);
  oa.y = (__bf16)((float)a.y * c.y - (float)b.y * sn.y);
  oa.z = (__bf16)((float)a.z * c.z - (float)b.z * sn.z);
  oa.w = (__bf16)((float)a.w * c.w - (float)b.w * sn.w);
  ob.x = (__bf16)((float)b.x * c.x + (float)a.x * sn.x);
  ob.y = (__bf16)((float)b.y * c.y + (float)a.y * sn.y);
  ob.z = (__bf16)((float)b.z * c.z + (float)a.z * sn.z);
  ob.w = (__bf16)((float)b.w * c.w + (float)a.w * sn.w);
  *(bf16x4*)&p[d] = oa;
  *(bf16x4*)&p[d + 64] = ob;
}

// ---------------- GEMM: C(M,N) = A(M,K,bf16) * W(K,N,f32) ----------------
// BM = MR*64, BN=64, BK=64. 4 waves, wave w owns rows [w*MR*16, (w+1)*MR*16).
// r19 post-mortem: measured rates show MR=2 @ 3 blk/CU (600 TF) beats
// MR=4 @ 2 blk/CU (510 TF) with the same 3-stage pipeline -> QKV moves to
// MR=2, grid (96,8). Everything else is the r14 checkpoint verbatim.
// B: reg-staged f32, k-pair packed, b128 to Bp[kp][16c][4] at
//    cphys=(nn>>2)^(kp&7) [r10-PROVEN 0 conflicts]. Frag: 4 b32, 2-way free.
// A: DMA-staged bf16, XOR chunk swizzle (proven 0-conflict).
// MODE 0 (MR=2): f32 C, grid (64,8), 48KB LDS -> 3 blocks/CU.
// MODE 1 (MR=2): QKV split, grid (96,8), 48KB LDS -> 3 blocks/CU.
template <int MODE, int MR>
__global__ __launch_bounds__(256, (MR == 2) ? 3 : 2)
void k_gemm(const __bf16* __restrict__ A,
            const float* __restrict__ W0,
            const float* __restrict__ W1,
            const float* __restrict__ W2,
            float* __restrict__ C,
            __bf16* __restrict__ Qb,
            __bf16* __restrict__ Kb,
            __bf16* __restrict__ Vt) {
  __shared__ __bf16 As[2][MR * 64 * 64];
  __shared__ unsigned Bp[2][32 * 64];
  const int bm = blockIdx.y, bn = blockIdx.x;
  const int K = DIN, NT = K / 64;

  const float* Wsrc; int ldb, nloc;
  if (MODE == 0) { Wsrc = W0; ldb = 4096; nloc = bn * 64; }
  else {
    if (bn < 64)      { Wsrc = W0; ldb = 4096; nloc = bn * 64; }
    else if (bn < 80) { Wsrc = W1; ldb = 1024; nloc = (bn - 64) * 64; }
    else              { Wsrc = W2; ldb = 1024; nloc = (bn - 80) * 64; }
  }

  const int tid = threadIdx.x, w = tid >> 6;
  const int l = tid & 63, l15 = l & 15, g4 = l >> 4;

  const __bf16* Asrc = A + (size_t)(bm * MR * 64) * K;

  f32x4 acc[MR][4];
#pragma unroll
  for (int i = 0; i < MR; ++i)
#pragma unroll
    for (int j = 0; j < 4; ++j)
#pragma unroll
      for (int r = 0; r < 4; ++r) acc[i][j][r] = 0.f;

  // B staging: TWO named reg sets (3-stage pipeline; rule-#20 static indexing)
  float4 bregA[2][2], bregB[2][2];
  const int kp_s[2] = {tid >> 4, 16 + (tid >> 4)};
  const int nn_s = (tid & 15) * 4;

  auto loadB = [&](int t, float4 (&br)[2][2]) {
    if (t >= NT) return;
#pragma unroll
    for (int p = 0; p < 2; ++p) {
      const float* src = Wsrc + (size_t)(t * 64 + 2 * kp_s[p]) * ldb + nloc + nn_s;
      br[p][0] = *(const float4*)src;
      br[p][1] = *(const float4*)(src + ldb);
    }
  };
  auto writeB = [&](float4 (&br)[2][2], unsigned* dst) {
#pragma unroll
    for (int p = 0; p < 2; ++p) {
      int kp = kp_s[p];
      int cphys = (nn_s >> 2) ^ (kp & 7);
      uint4 d;
      d.x = pack2bf(br[p][0].x, br[p][1].x);
      d.y = pack2bf(br[p][0].y, br[p][1].y);
      d.z = pack2bf(br[p][0].z, br[p][1].z);
      d.w = pack2bf(br[p][0].w, br[p][1].w);
      *(uint4*)&dst[kp * 64 + cphys * 4] = d;
    }
  };
  auto issueA = [&](int t, __bf16* dst) {
#pragma unroll
    for (int p = 0; p < MR * 2; ++p) {
      int c = p * 256 + tid;
      int row = c >> 3, gc = (c & 7) ^ (row & 7);
      gload_lds16(Asrc + (size_t)row * K + t * 64 + gc * 8, dst + (p * 256 + w * 64) * 8);
    }
  };
  auto compute = [&](const __bf16* Ab, const unsigned* Bp_) {
    bf16x8 af[MR][2];
#pragma unroll
    for (int i = 0; i < MR; ++i) {
      int m = w * MR * 16 + i * 16 + l15;
#pragma unroll
      for (int kk = 0; kk < 2; ++kk)
        af[i][kk] = *(const bf16x8*)((const char*)Ab + m * 128 + (((kk * 4 + g4) ^ (m & 7)) << 4));
    }
#pragma unroll
    for (int kk = 0; kk < 2; ++kk)
#pragma unroll
      for (int j = 0; j < 4; ++j) {
        int n = j * 16 + l15;
        union { unsigned u[4]; bf16x8 v; } fb;
#pragma unroll
        for (int d = 0; d < 4; ++d) {
          int kp = kk * 16 + g4 * 4 + d;
          fb.u[d] = Bp_[kp * 64 + (((n >> 2) ^ (kp & 7)) << 2) + (n & 3)];
        }
#pragma unroll
        for (int i = 0; i < MR; ++i)
          acc[i][j] = __builtin_amdgcn_mfma_f32_16x16x32_bf16(af[i][kk], fb.v, acc[i][j], 0, 0, 0);
      }
  };

  // prologue: B loads for tiles 0 and 1 in flight; tile 0 staged
  loadB(0, bregA);
  loadB(1, bregB);
  issueA(0, As[0]);
  writeB(bregA, Bp[0]);     // compiler inserts the vmcnt wait for breg deps
  __syncthreads();          // drains A DMA + ds_writes

  for (int t = 0; t < NT; t += 2) {
    // --- half 1: compute tile t; stage t+1; launch B loads for t+2 ---
    loadB(t + 2, bregA);    // oldest issue: ~2 k-steps before its writeB
    issueA(t + 1, As[1]);
    compute(As[0], Bp[0]);
    writeB(bregB, Bp[1]);   // tile t+1 (loaded ~2 steps ago -> landed)
    __syncthreads();
    // --- half 2: compute tile t+1; stage t+2; launch B loads for t+3 ---
    loadB(t + 3, bregB);
    if (t + 2 < NT) issueA(t + 2, As[0]);
    compute(As[1], Bp[1]);
    if (t + 2 < NT) writeB(bregA, Bp[0]);  // tile t+2
    __syncthreads();
  }

  // ---- epilogue ----
  if constexpr (MODE == 0) {
#pragma unroll
    for (int i = 0; i < MR; ++i)
#pragma unroll
      for (int j = 0; j < 4; ++j)
#pragma unroll
        for (int r = 0; r < 4; ++r) {
          size_t row = bm * MR * 64 + w * MR * 16 + i * 16 + g4 * 4 + r;
          size_t col = bn * 64 + j * 16 + l15;
          C[row * 4096 + col] = acc[i][j][r];
        }
  } else {
    if (bn < 80) {
      __bf16* dst = (bn < 64) ? Qb : Kb;
      int ldc = (bn < 64) ? 4096 : 1024;
#pragma unroll
      for (int i = 0; i < MR; ++i)
#pragma unroll
        for (int j = 0; j < 4; ++j)
#pragma unroll
          for (int r = 0; r < 4; ++r) {
            size_t row = bm * MR * 64 + w * MR * 16 + i * 16 + g4 * 4 + r;
            size_t col = (size_t)nloc + j * 16 + l15;
            dst[row * ldc + col] = (__bf16)acc[i][j][r];
          }
    } else {
      // V: write transposed -> Vt[n][s]
#pragma unroll
      for (int i = 0; i < MR; ++i)
#pragma unroll
        for (int j = 0; j < 4; ++j) {
          size_t n = (size_t)nloc + j * 16 + l15;
          size_t m0 = bm * MR * 64 + w * MR * 16 + i * 16 + g4 * 4;
          bf16x4 v;
          v.x = (__bf16)acc[i][j][0]; v.y = (__bf16)acc[i][j][1];
          v.z = (__bf16)acc[i][j][2]; v.w = (__bf16)acc[i][j][3];
          *(bf16x4*)&Vt[n * 1024 + m0] = v;
        }
    }
  }
}

// ---------------- flash attention (round-2 proven) ----------------
__global__ __launch_bounds__(256) void k_attn(const __bf16* __restrict__ Q,
                                              const __bf16* __restrict__ Kb,
                                              const __bf16* __restrict__ Vt,
                                              __bf16* __restrict__ ctx) {
  __shared__ __align__(16) char lds_raw[65536];
  __bf16* Ks = (__bf16*)lds_raw;
  __bf16* Vs = (__bf16*)(lds_raw + 32768);

  const int h = blockIdx.y, g = h >> 2;
  const int q0 = blockIdx.x * 64;
  const int tid = threadIdx.x, w = tid >> 6, l = tid & 63;
  const int l15 = l & 15, g4 = l >> 4;
  const float scale = 0.08838834764831845f;

  bf16x8 qf[4];
  const int qrow = q0 + w * 16 + l15;
#pragma unroll
  for (int ks = 0; ks < 4; ++ks)
    qf[ks] = *(const bf16x8*)&Q[(size_t)qrow * (NH * HD) + h * HD + ks * 32 + g4 * 8];

  f32x4 acc[8];
#pragma unroll
  for (int i = 0; i < 8; ++i)
#pragma unroll
    for (int r = 0; r < 4; ++r) acc[i][r] = 0.f;
  float m_run = -__builtin_inff(), l_run = 0.f;

  const int ntiles = (q0 + 64 + 127) >> 7;
  for (int kt = 0; kt < ntiles; ++kt) {
    const int kv0 = kt * 128;
#pragma unroll
    for (int p = 0; p < 8; ++p) {
      int c = p * 256 + tid;
      int row = c >> 4, cc = c & 15;
      gload_lds16(&Kb[(size_t)(kv0 + row) * (NG * HD) + g * HD + ((cc ^ (row & 7)) << 3)],
                  &Ks[(p * 256 + w * 64) * 8]);
      gload_lds16(&Vt[(size_t)(g * HD + row) * S_LEN + kv0 + ((cc ^ (row & 7)) << 3)],
                  &Vs[(p * 256 + w * 64) * 8]);
    }
    __syncthreads();

    float sreg[8][4];
    const bool need_mask = (kv0 + 127 > q0);
#pragma unroll
    for (int tf = 0; tf < 8; ++tf) {
      f32x4 sa;
#pragma unroll
      for (int r = 0; r < 4; ++r) sa[r] = 0.f;
      int t_loc = tf * 16 + l15;
#pragma unroll
      for (int ks = 0; ks < 4; ++ks) {
        bf16x8 kf = *(const bf16x8*)((const char*)Ks + t_loc * 256 + (((ks * 4 + g4) ^ (t_loc & 7)) << 4));
        sa = __builtin_amdgcn_mfma_f32_16x16x32_bf16(kf, qf[ks], sa, 0, 0, 0);
      }
#pragma unroll
      for (int r = 0; r < 4; ++r) {
        float v = sa[r] * scale;
        if (need_mask && (kv0 + tf * 16 + g4 * 4 + r) > qrow) v = -__builtin_inff();
        sreg[tf][r] = v;
      }
    }
    float mx = -__builtin_inff();
#pragma unroll
    for (int tf = 0; tf < 8; ++tf)
#pragma unroll
      for (int r = 0; r < 4; ++r) mx = fmaxf(mx, sreg[tf][r]);
    mx = fmaxf(mx, __shfl_xor(mx, 16));
    mx = fmaxf(mx, __shfl_xor(mx, 32));
    const float m_new = fmaxf(m_run, mx);
    const float alpha = __expf(m_run - m_new);
    float ssum = 0.f;
#pragma unroll
    for (int tf = 0; tf < 8; ++tf)
#pragma unroll
      for (int r = 0; r < 4; ++r) {
        sreg[tf][r] = __expf(sreg[tf][r] - m_new);
        ssum += sreg[tf][r];
      }
    ssum += __shfl_xor(ssum, 16);
    ssum += __shfl_xor(ssum, 32);
    l_run = l_run * alpha + ssum;
    m_run = m_new;
    float ar[4];
#pragma unroll
    for (int r = 0; r < 4; ++r) ar[r] = __shfl(alpha, g4 * 4 + r);
#pragma unroll
    for (int nf = 0; nf < 8; ++nf)
#pragma unroll
      for (int r = 0; r < 4; ++r) acc[nf][r] *= ar[r];

    __syncthreads();

    char* pb = lds_raw + w * 4096;
#pragma unroll
    for (int tf = 0; tf < 8; ++tf) {
      int chunkc = 2 * tf + (g4 >> 1);
      int addr = l15 * 256 + ((chunkc ^ (l15 & 7)) << 4) + ((g4 & 1) << 3);
      *(unsigned*)(pb + addr)     = pack2bf(sreg[tf][0], sreg[tf][1]);
      *(unsigned*)(pb + addr + 4) = pack2bf(sreg[tf][2], sreg[tf][3]);
    }
    asm volatile("s_waitcnt lgkmcnt(0)" ::: "memory");
    bf16x8 pf[4];
#pragma unroll
    for (int ks = 0; ks < 4; ++ks)
      pf[ks] = *(const bf16x8*)(pb + l15 * 256 + (((ks * 4 + g4) ^ (l15 & 7)) << 4));
#pragma unroll
    for (int nf = 0; nf < 8; ++nf) {
      int d_loc = nf * 16 + l15;
#pragma unroll
      for (int ks = 0; ks < 4; ++ks) {
        bf16x8 vf = *(const bf16x8*)((const char*)Vs + d_loc * 256 + (((ks * 4 + g4) ^ (d_loc & 7)) << 4));
        acc[nf] = __builtin_amdgcn_mfma_f32_16x16x32_bf16(pf[ks], vf, acc[nf], 0, 0, 0);
      }
    }
    __syncthreads();
  }
  float li[4];
#pragma unroll
  for (int r = 0; r < 4; ++r) li[r] = 1.f / __shfl(l_run, g4 * 4 + r);
#pragma unroll
  for (int nf = 0; nf < 8; ++nf)
#pragma unroll
    for (int r = 0; r < 4; ++r) {
      size_t row = q0 + w * 16 + g4 * 4 + r;
      size_t col = (size_t)h * HD + nf * 16 + l15;
      ctx[row * (NH * HD) + col] = (__bf16)(acc[nf][r] * li[r]);
    }
}

// ---------------- host ----------------
extern "C" void kernel_launch(void* const* d_in, const int* in_sizes, int n_in,
                              void* d_out, int out_size, void* d_ws, size_t ws_size,
                              hipStream_t stream) {
  const float* x    = (const float*)d_in[0];
  const float* cosT = (const float*)d_in[2];
  const float* sinT = (const float*)d_in[3];
  const float* Wq   = (const float*)d_in[4];
  const float* Wk   = (const float*)d_in[5];
  const float* Wv   = (const float*)d_in[6];
  const float* Wo   = (const float*)d_in[7];
  float* out = (float*)d_out;

  char* ws = (char*)d_ws;
  const size_t MB = 1u << 20;
  __bf16* xb   = (__bf16*)(ws + 0);        // 8 MB : x bf16; reused as ctx after QKV
  __bf16* Qb   = (__bf16*)(ws + 8 * MB);   // 8 MB : Q, roped in-place
  __bf16* Kbuf = (__bf16*)(ws + 16 * MB);  // 2 MB : K, roped in-place
  __bf16* Vtb  = (__bf16*)(ws + 18 * MB);  // 2 MB : V^T (direct from epilogue)
  __bf16* ctxb = (__bf16*)(ws + 0);        // aliases xb (dead after QKV GEMM)

  k_cast<<<4096, 256, 0, stream>>>(x, xb, (S_LEN * DIN) / 4);

  // fused QKV: f32 weights direct, BM=128 (MR=2), 3 blocks/CU. grid (96,8).
  k_gemm<1, 2><<<dim3(96, 8), 256, 0, stream>>>(xb, Wq, Wk, Wv, nullptr, Qb, Kbuf, Vtb);

  k_rope<<<2560, 256, 0, stream>>>(Qb, Kbuf, cosT, sinT);

  k_attn<<<dim3(16, 32), 256, 0, stream>>>(Qb, Kbuf, Vtb, ctxb);

  // out = ctx * Wo, f32 out, BM=128 (MR=2), 3 blocks/CU. grid (64,8).
  k_gemm<0, 2><<<dim3(64, 8), 256, 0, stream>>>(ctxb, Wo, nullptr, nullptr, out,
                                                nullptr, nullptr, nullptr);
}

// Round 21
// 196.615 us; speedup vs baseline: 5.5856x; 1.0036x over previous
//
#include <hip/hip_runtime.h>
#include <hip/hip_bf16.h>

#define S_LEN 1024
#define DIN 4096
#define NH 32
#define NG 8
#define HD 128

typedef __bf16 bf16x8 __attribute__((ext_vector_type(8)));
typedef __bf16 bf16x4 __attribute__((ext_vector_type(4)));
typedef float f32x4 __attribute__((ext_vector_type(4)));

__device__ __forceinline__ void gload_lds16(const void* g, void* l) {
  __builtin_amdgcn_global_load_lds(
      (const __attribute__((address_space(1))) unsigned int*)g,
      (__attribute__((address_space(3))) unsigned int*)l, 16, 0, 0);
}

__device__ __forceinline__ unsigned pack2bf(float a, float b) {
  union { __bf16 h[2]; unsigned u; } x;
  x.h[0] = (__bf16)a; x.h[1] = (__bf16)b;
  return x.u;
}

// ---------------- cast x: f32 -> bf16 (the only prep) ----------------
__global__ __launch_bounds__(256) void k_cast(const float* __restrict__ in,
                                              __bf16* __restrict__ out, int n4) {
  int i = blockIdx.x * 256 + threadIdx.x;
  if (i >= n4) return;
  const float4 v = ((const float4*)in)[i];
  bf16x4 o;
  o.x = (__bf16)v.x; o.y = (__bf16)v.y; o.z = (__bf16)v.z; o.w = (__bf16)v.w;
  ((bf16x4*)out)[i] = o;
}

// ---------------- RoPE, vectorized: 4 d-pairs per thread ----------------
__global__ __launch_bounds__(256) void k_rope(__bf16* __restrict__ Q, __bf16* __restrict__ Kb,
                                              const float* __restrict__ cosT,
                                              const float* __restrict__ sinT) {
  int idx = blockIdx.x * 256 + threadIdx.x;
  int d = (idx & 15) * 4;
  int row = idx >> 4;
  __bf16* p; int s;
  if (row < S_LEN * NH) { p = Q + (size_t)row * HD; s = row >> 5; }
  else { int r = row - S_LEN * NH; p = Kb + (size_t)r * HD; s = r >> 3; }
  const float4 c = *(const float4*)&cosT[s * HD + d];
  const float4 sn = *(const float4*)&sinT[s * HD + d];
  bf16x4 a = *(const bf16x4*)&p[d];
  bf16x4 b = *(const bf16x4*)&p[d + 64];
  bf16x4 oa, ob;
  oa.x = (__bf16)((float)a.x * c.x - (float)b.x * sn.x);
  oa.y = (__bf16)((float)a.y * c.y - (float)b.y * sn.y);
  oa.z = (__bf16)((float)a.z * c.z - (float)b.z * sn.z);
  oa.w = (__bf16)((float)a.w * c.w - (float)b.w * sn.w);
  ob.x = (__bf16)((float)b.x * c.x + (float)a.x * sn.x);
  ob.y = (__bf16)((float)b.y * c.y + (float)a.y * sn.y);
  ob.z = (__bf16)((float)b.z * c.z + (float)a.z * sn.z);
  ob.w = (__bf16)((float)b.w * c.w + (float)a.w * sn.w);
  *(bf16x4*)&p[d] = oa;
  *(bf16x4*)&p[d + 64] = ob;
}

// ---------------- GEMM: C(M,N) = A(M,K,bf16) * W(K,N,f32) ----------------
// FINAL (r14 checkpoint, session best 196.4us; r19/r20 confirm 197-201 noise
// band). Double-buffered LDS, 3-stage B prefetch (2 named breg sets,
// loadB(t+2) ~2 k-steps before its writeB), plain __syncthreads.
// Falsified alternatives: hand-vmcnt (r15 +22us), MR=8 (r16 +34), 4 blk/CU
// (r17 spills), single-buffer (r18 +30/dispatch), XCD remap (r13 +21),
// QKV MR=2 (r20 +11). B: reg-staged f32, k-pair packed, b128 to
// Bp[kp][16c][4] at cphys=(nn>>2)^(kp&7) [0 conflicts measured].
// A: DMA-staged bf16, XOR chunk swizzle [0 conflicts measured].
// MODE 0 (MR=2): f32 C, grid (64,8), 48KB LDS -> 3 blocks/CU.
// MODE 1 (MR=4): QKV split, grid (96,4), 80KB LDS -> 2 blocks/CU.
template <int MODE, int MR>
__global__ __launch_bounds__(256, (MR == 2) ? 3 : 2)
void k_gemm(const __bf16* __restrict__ A,
            const float* __restrict__ W0,
            const float* __restrict__ W1,
            const float* __restrict__ W2,
            float* __restrict__ C,
            __bf16* __restrict__ Qb,
            __bf16* __restrict__ Kb,
            __bf16* __restrict__ Vt) {
  __shared__ __bf16 As[2][MR * 64 * 64];
  __shared__ unsigned Bp[2][32 * 64];
  const int bm = blockIdx.y, bn = blockIdx.x;
  const int K = DIN, NT = K / 64;

  const float* Wsrc; int ldb, nloc;
  if (MODE == 0) { Wsrc = W0; ldb = 4096; nloc = bn * 64; }
  else {
    if (bn < 64)      { Wsrc = W0; ldb = 4096; nloc = bn * 64; }
    else if (bn < 80) { Wsrc = W1; ldb = 1024; nloc = (bn - 64) * 64; }
    else              { Wsrc = W2; ldb = 1024; nloc = (bn - 80) * 64; }
  }

  const int tid = threadIdx.x, w = tid >> 6;
  const int l = tid & 63, l15 = l & 15, g4 = l >> 4;

  const __bf16* Asrc = A + (size_t)(bm * MR * 64) * K;

  f32x4 acc[MR][4];
#pragma unroll
  for (int i = 0; i < MR; ++i)
#pragma unroll
    for (int j = 0; j < 4; ++j)
#pragma unroll
      for (int r = 0; r < 4; ++r) acc[i][j][r] = 0.f;

  // B staging: TWO named reg sets (3-stage pipeline; rule-#20 static indexing)
  float4 bregA[2][2], bregB[2][2];
  const int kp_s[2] = {tid >> 4, 16 + (tid >> 4)};
  const int nn_s = (tid & 15) * 4;

  auto loadB = [&](int t, float4 (&br)[2][2]) {
    if (t >= NT) return;
#pragma unroll
    for (int p = 0; p < 2; ++p) {
      const float* src = Wsrc + (size_t)(t * 64 + 2 * kp_s[p]) * ldb + nloc + nn_s;
      br[p][0] = *(const float4*)src;
      br[p][1] = *(const float4*)(src + ldb);
    }
  };
  auto writeB = [&](float4 (&br)[2][2], unsigned* dst) {
#pragma unroll
    for (int p = 0; p < 2; ++p) {
      int kp = kp_s[p];
      int cphys = (nn_s >> 2) ^ (kp & 7);
      uint4 d;
      d.x = pack2bf(br[p][0].x, br[p][1].x);
      d.y = pack2bf(br[p][0].y, br[p][1].y);
      d.z = pack2bf(br[p][0].z, br[p][1].z);
      d.w = pack2bf(br[p][0].w, br[p][1].w);
      *(uint4*)&dst[kp * 64 + cphys * 4] = d;
    }
  };
  auto issueA = [&](int t, __bf16* dst) {
#pragma unroll
    for (int p = 0; p < MR * 2; ++p) {
      int c = p * 256 + tid;
      int row = c >> 3, gc = (c & 7) ^ (row & 7);
      gload_lds16(Asrc + (size_t)row * K + t * 64 + gc * 8, dst + (p * 256 + w * 64) * 8);
    }
  };
  auto compute = [&](const __bf16* Ab, const unsigned* Bp_) {
    bf16x8 af[MR][2];
#pragma unroll
    for (int i = 0; i < MR; ++i) {
      int m = w * MR * 16 + i * 16 + l15;
#pragma unroll
      for (int kk = 0; kk < 2; ++kk)
        af[i][kk] = *(const bf16x8*)((const char*)Ab + m * 128 + (((kk * 4 + g4) ^ (m & 7)) << 4));
    }
#pragma unroll
    for (int kk = 0; kk < 2; ++kk)
#pragma unroll
      for (int j = 0; j < 4; ++j) {
        int n = j * 16 + l15;
        union { unsigned u[4]; bf16x8 v; } fb;
#pragma unroll
        for (int d = 0; d < 4; ++d) {
          int kp = kk * 16 + g4 * 4 + d;
          fb.u[d] = Bp_[kp * 64 + (((n >> 2) ^ (kp & 7)) << 2) + (n & 3)];
        }
#pragma unroll
        for (int i = 0; i < MR; ++i)
          acc[i][j] = __builtin_amdgcn_mfma_f32_16x16x32_bf16(af[i][kk], fb.v, acc[i][j], 0, 0, 0);
      }
  };

  // prologue: B loads for tiles 0 and 1 in flight; tile 0 staged
  loadB(0, bregA);
  loadB(1, bregB);
  issueA(0, As[0]);
  writeB(bregA, Bp[0]);     // compiler inserts the vmcnt wait for breg deps
  __syncthreads();          // drains A DMA + ds_writes

  for (int t = 0; t < NT; t += 2) {
    // --- half 1: compute tile t; stage t+1; launch B loads for t+2 ---
    loadB(t + 2, bregA);    // oldest issue: ~2 k-steps before its writeB
    issueA(t + 1, As[1]);
    compute(As[0], Bp[0]);
    writeB(bregB, Bp[1]);   // tile t+1 (loaded ~2 steps ago -> landed)
    __syncthreads();
    // --- half 2: compute tile t+1; stage t+2; launch B loads for t+3 ---
    loadB(t + 3, bregB);
    if (t + 2 < NT) issueA(t + 2, As[0]);
    compute(As[1], Bp[1]);
    if (t + 2 < NT) writeB(bregA, Bp[0]);  // tile t+2
    __syncthreads();
  }

  // ---- epilogue ----
  if constexpr (MODE == 0) {
#pragma unroll
    for (int i = 0; i < MR; ++i)
#pragma unroll
      for (int j = 0; j < 4; ++j)
#pragma unroll
        for (int r = 0; r < 4; ++r) {
          size_t row = bm * MR * 64 + w * MR * 16 + i * 16 + g4 * 4 + r;
          size_t col = bn * 64 + j * 16 + l15;
          C[row * 4096 + col] = acc[i][j][r];
        }
  } else {
    if (bn < 80) {
      __bf16* dst = (bn < 64) ? Qb : Kb;
      int ldc = (bn < 64) ? 4096 : 1024;
#pragma unroll
      for (int i = 0; i < MR; ++i)
#pragma unroll
        for (int j = 0; j < 4; ++j)
#pragma unroll
          for (int r = 0; r < 4; ++r) {
            size_t row = bm * MR * 64 + w * MR * 16 + i * 16 + g4 * 4 + r;
            size_t col = (size_t)nloc + j * 16 + l15;
            dst[row * ldc + col] = (__bf16)acc[i][j][r];
          }
    } else {
      // V: write transposed -> Vt[n][s]
#pragma unroll
      for (int i = 0; i < MR; ++i)
#pragma unroll
        for (int j = 0; j < 4; ++j) {
          size_t n = (size_t)nloc + j * 16 + l15;
          size_t m0 = bm * MR * 64 + w * MR * 16 + i * 16 + g4 * 4;
          bf16x4 v;
          v.x = (__bf16)acc[i][j][0]; v.y = (__bf16)acc[i][j][1];
          v.z = (__bf16)acc[i][j][2]; v.w = (__bf16)acc[i][j][3];
          *(bf16x4*)&Vt[n * 1024 + m0] = v;
        }
    }
  }
}

// ---------------- flash attention (round-2 proven) ----------------
__global__ __launch_bounds__(256) void k_attn(const __bf16* __restrict__ Q,
                                              const __bf16* __restrict__ Kb,
                                              const __bf16* __restrict__ Vt,
                                              __bf16* __restrict__ ctx) {
  __shared__ __align__(16) char lds_raw[65536];
  __bf16* Ks = (__bf16*)lds_raw;
  __bf16* Vs = (__bf16*)(lds_raw + 32768);

  const int h = blockIdx.y, g = h >> 2;
  const int q0 = blockIdx.x * 64;
  const int tid = threadIdx.x, w = tid >> 6, l = tid & 63;
  const int l15 = l & 15, g4 = l >> 4;
  const float scale = 0.08838834764831845f;

  bf16x8 qf[4];
  const int qrow = q0 + w * 16 + l15;
#pragma unroll
  for (int ks = 0; ks < 4; ++ks)
    qf[ks] = *(const bf16x8*)&Q[(size_t)qrow * (NH * HD) + h * HD + ks * 32 + g4 * 8];

  f32x4 acc[8];
#pragma unroll
  for (int i = 0; i < 8; ++i)
#pragma unroll
    for (int r = 0; r < 4; ++r) acc[i][r] = 0.f;
  float m_run = -__builtin_inff(), l_run = 0.f;

  const int ntiles = (q0 + 64 + 127) >> 7;
  for (int kt = 0; kt < ntiles; ++kt) {
    const int kv0 = kt * 128;
#pragma unroll
    for (int p = 0; p < 8; ++p) {
      int c = p * 256 + tid;
      int row = c >> 4, cc = c & 15;
      gload_lds16(&Kb[(size_t)(kv0 + row) * (NG * HD) + g * HD + ((cc ^ (row & 7)) << 3)],
                  &Ks[(p * 256 + w * 64) * 8]);
      gload_lds16(&Vt[(size_t)(g * HD + row) * S_LEN + kv0 + ((cc ^ (row & 7)) << 3)],
                  &Vs[(p * 256 + w * 64) * 8]);
    }
    __syncthreads();

    float sreg[8][4];
    const bool need_mask = (kv0 + 127 > q0);
#pragma unroll
    for (int tf = 0; tf < 8; ++tf) {
      f32x4 sa;
#pragma unroll
      for (int r = 0; r < 4; ++r) sa[r] = 0.f;
      int t_loc = tf * 16 + l15;
#pragma unroll
      for (int ks = 0; ks < 4; ++ks) {
        bf16x8 kf = *(const bf16x8*)((const char*)Ks + t_loc * 256 + (((ks * 4 + g4) ^ (t_loc & 7)) << 4));
        sa = __builtin_amdgcn_mfma_f32_16x16x32_bf16(kf, qf[ks], sa, 0, 0, 0);
      }
#pragma unroll
      for (int r = 0; r < 4; ++r) {
        float v = sa[r] * scale;
        if (need_mask && (kv0 + tf * 16 + g4 * 4 + r) > qrow) v = -__builtin_inff();
        sreg[tf][r] = v;
      }
    }
    float mx = -__builtin_inff();
#pragma unroll
    for (int tf = 0; tf < 8; ++tf)
#pragma unroll
      for (int r = 0; r < 4; ++r) mx = fmaxf(mx, sreg[tf][r]);
    mx = fmaxf(mx, __shfl_xor(mx, 16));
    mx = fmaxf(mx, __shfl_xor(mx, 32));
    const float m_new = fmaxf(m_run, mx);
    const float alpha = __expf(m_run - m_new);
    float ssum = 0.f;
#pragma unroll
    for (int tf = 0; tf < 8; ++tf)
#pragma unroll
      for (int r = 0; r < 4; ++r) {
        sreg[tf][r] = __expf(sreg[tf][r] - m_new);
        ssum += sreg[tf][r];
      }
    ssum += __shfl_xor(ssum, 16);
    ssum += __shfl_xor(ssum, 32);
    l_run = l_run * alpha + ssum;
    m_run = m_new;
    float ar[4];
#pragma unroll
    for (int r = 0; r < 4; ++r) ar[r] = __shfl(alpha, g4 * 4 + r);
#pragma unroll
    for (int nf = 0; nf < 8; ++nf)
#pragma unroll
      for (int r = 0; r < 4; ++r) acc[nf][r] *= ar[r];

    __syncthreads();

    char* pb = lds_raw + w * 4096;
#pragma unroll
    for (int tf = 0; tf < 8; ++tf) {
      int chunkc = 2 * tf + (g4 >> 1);
      int addr = l15 * 256 + ((chunkc ^ (l15 & 7)) << 4) + ((g4 & 1) << 3);
      *(unsigned*)(pb + addr)     = pack2bf(sreg[tf][0], sreg[tf][1]);
      *(unsigned*)(pb + addr + 4) = pack2bf(sreg[tf][2], sreg[tf][3]);
    }
    asm volatile("s_waitcnt lgkmcnt(0)" ::: "memory");
    bf16x8 pf[4];
#pragma unroll
    for (int ks = 0; ks < 4; ++ks)
      pf[ks] = *(const bf16x8*)(pb + l15 * 256 + (((ks * 4 + g4) ^ (l15 & 7)) << 4));
#pragma unroll
    for (int nf = 0; nf < 8; ++nf) {
      int d_loc = nf * 16 + l15;
#pragma unroll
      for (int ks = 0; ks < 4; ++ks) {
        bf16x8 vf = *(const bf16x8*)((const char*)Vs + d_loc * 256 + (((ks * 4 + g4) ^ (d_loc & 7)) << 4));
        acc[nf] = __builtin_amdgcn_mfma_f32_16x16x32_bf16(pf[ks], vf, acc[nf], 0, 0, 0);
      }
    }
    __syncthreads();
  }
  float li[4];
#pragma unroll
  for (int r = 0; r < 4; ++r) li[r] = 1.f / __shfl(l_run, g4 * 4 + r);
#pragma unroll
  for (int nf = 0; nf < 8; ++nf)
#pragma unroll
    for (int r = 0; r < 4; ++r) {
      size_t row = q0 + w * 16 + g4 * 4 + r;
      size_t col = (size_t)h * HD + nf * 16 + l15;
      ctx[row * (NH * HD) + col] = (__bf16)(acc[nf][r] * li[r]);
    }
}

// ---------------- host ----------------
extern "C" void kernel_launch(void* const* d_in, const int* in_sizes, int n_in,
                              void* d_out, int out_size, void* d_ws, size_t ws_size,
                              hipStream_t stream) {
  const float* x    = (const float*)d_in[0];
  const float* cosT = (const float*)d_in[2];
  const float* sinT = (const float*)d_in[3];
  const float* Wq   = (const float*)d_in[4];
  const float* Wk   = (const float*)d_in[5];
  const float* Wv   = (const float*)d_in[6];
  const float* Wo   = (const float*)d_in[7];
  float* out = (float*)d_out;

  char* ws = (char*)d_ws;
  const size_t MB = 1u << 20;
  __bf16* xb   = (__bf16*)(ws + 0);        // 8 MB : x bf16; reused as ctx after QKV
  __bf16* Qb   = (__bf16*)(ws + 8 * MB);   // 8 MB : Q, roped in-place
  __bf16* Kbuf = (__bf16*)(ws + 16 * MB);  // 2 MB : K, roped in-place
  __bf16* Vtb  = (__bf16*)(ws + 18 * MB);  // 2 MB : V^T (direct from epilogue)
  __bf16* ctxb = (__bf16*)(ws + 0);        // aliases xb (dead after QKV GEMM)

  k_cast<<<4096, 256, 0, stream>>>(x, xb, (S_LEN * DIN) / 4);

  // fused QKV: f32 weights direct, BM=256 (MR=4), 3-stage B prefetch. grid (96,4).
  k_gemm<1, 4><<<dim3(96, 4), 256, 0, stream>>>(xb, Wq, Wk, Wv, nullptr, Qb, Kbuf, Vtb);

  k_rope<<<2560, 256, 0, stream>>>(Qb, Kbuf, cosT, sinT);

  k_attn<<<dim3(16, 32), 256, 0, stream>>>(Qb, Kbuf, Vtb, ctxb);

  // out = ctx * Wo, f32 out, BM=128 (MR=2), 3 blocks/CU. grid (64,8).
  k_gemm<0, 2><<<dim3(64, 8), 256, 0, stream>>>(ctxb, Wo, nullptr, nullptr, out,
                                                nullptr, nullptr, nullptr);
}

// Round 22
// 191.429 us; speedup vs baseline: 5.7369x; 1.0271x over previous
//
#include <hip/hip_runtime.h>
#include <hip/hip_bf16.h>

#define S_LEN 1024
#define DIN 4096
#define NH 32
#define NG 8
#define HD 128

typedef __bf16 bf16x8 __attribute__((ext_vector_type(8)));
typedef __bf16 bf16x4 __attribute__((ext_vector_type(4)));
typedef float f32x4 __attribute__((ext_vector_type(4)));

__device__ __forceinline__ void gload_lds16(const void* g, void* l) {
  __builtin_amdgcn_global_load_lds(
      (const __attribute__((address_space(1))) unsigned int*)g,
      (__attribute__((address_space(3))) unsigned int*)l, 16, 0, 0);
}

__device__ __forceinline__ unsigned pack2bf(float a, float b) {
  union { __bf16 h[2]; unsigned u; } x;
  x.h[0] = (__bf16)a; x.h[1] = (__bf16)b;
  return x.u;
}

// ---------------- cast x: f32 -> bf16 (the only prep) ----------------
__global__ __launch_bounds__(256) void k_cast(const float* __restrict__ in,
                                              __bf16* __restrict__ out, int n4) {
  int i = blockIdx.x * 256 + threadIdx.x;
  if (i >= n4) return;
  const float4 v = ((const float4*)in)[i];
  bf16x4 o;
  o.x = (__bf16)v.x; o.y = (__bf16)v.y; o.z = (__bf16)v.z; o.w = (__bf16)v.w;
  ((bf16x4*)out)[i] = o;
}

// ---------------- RoPE, vectorized: 4 d-pairs per thread ----------------
__global__ __launch_bounds__(256) void k_rope(__bf16* __restrict__ Q, __bf16* __restrict__ Kb,
                                              const float* __restrict__ cosT,
                                              const float* __restrict__ sinT) {
  int idx = blockIdx.x * 256 + threadIdx.x;
  int d = (idx & 15) * 4;
  int row = idx >> 4;
  __bf16* p; int s;
  if (row < S_LEN * NH) { p = Q + (size_t)row * HD; s = row >> 5; }
  else { int r = row - S_LEN * NH; p = Kb + (size_t)r * HD; s = r >> 3; }
  const float4 c = *(const float4*)&cosT[s * HD + d];
  const float4 sn = *(const float4*)&sinT[s * HD + d];
  bf16x4 a = *(const bf16x4*)&p[d];
  bf16x4 b = *(const bf16x4*)&p[d + 64];
  bf16x4 oa, ob;
  oa.x = (__bf16)((float)a.x * c.x - (float)b.x * sn.x);
  oa.y = (__bf16)((float)a.y * c.y - (float)b.y * sn.y);
  oa.z = (__bf16)((float)a.z * c.z - (float)b.z * sn.z);
  oa.w = (__bf16)((float)a.w * c.w - (float)b.w * sn.w);
  ob.x = (__bf16)((float)b.x * c.x + (float)a.x * sn.x);
  ob.y = (__bf16)((float)b.y * c.y + (float)a.y * sn.y);
  ob.z = (__bf16)((float)b.z * c.z + (float)a.z * sn.z);
  ob.w = (__bf16)((float)b.w * c.w + (float)a.w * sn.w);
  *(bf16x4*)&p[d] = oa;
  *(bf16x4*)&p[d + 64] = ob;
}

// ---------------- GEMM: C(M,N) = A(M,K,bf16) * W(K,N,f32) ----------------
// FINAL (r14 checkpoint, session best 196.4us; r19/r20/r21 confirm 196-201
// noise band). Double-buffered LDS, 3-stage B prefetch (2 named breg sets,
// loadB(t+2) ~2 k-steps before its writeB), plain __syncthreads.
// Falsified alternatives: hand-vmcnt (r15 +22us), MR=8 (r16 +34), 4 blk/CU
// (r17 spills), single-buffer (r18 +30/dispatch), XCD remap on GEMM (r13 +21,
// breaks A-panel L3 residency), QKV MR=2 (r20 +11).
// B: reg-staged f32, k-pair packed, b128 to Bp[kp][16c][4] at
//    cphys=(nn>>2)^(kp&7) [0 conflicts measured].
// A: DMA-staged bf16, XOR chunk swizzle [0 conflicts measured].
// MODE 0 (MR=2): f32 C, grid (64,8), 48KB LDS -> 3 blocks/CU.
// MODE 1 (MR=4): QKV split, grid (96,4), 80KB LDS -> 2 blocks/CU.
template <int MODE, int MR>
__global__ __launch_bounds__(256, (MR == 2) ? 3 : 2)
void k_gemm(const __bf16* __restrict__ A,
            const float* __restrict__ W0,
            const float* __restrict__ W1,
            const float* __restrict__ W2,
            float* __restrict__ C,
            __bf16* __restrict__ Qb,
            __bf16* __restrict__ Kb,
            __bf16* __restrict__ Vt) {
  __shared__ __bf16 As[2][MR * 64 * 64];
  __shared__ unsigned Bp[2][32 * 64];
  const int bm = blockIdx.y, bn = blockIdx.x;
  const int K = DIN, NT = K / 64;

  const float* Wsrc; int ldb, nloc;
  if (MODE == 0) { Wsrc = W0; ldb = 4096; nloc = bn * 64; }
  else {
    if (bn < 64)      { Wsrc = W0; ldb = 4096; nloc = bn * 64; }
    else if (bn < 80) { Wsrc = W1; ldb = 1024; nloc = (bn - 64) * 64; }
    else              { Wsrc = W2; ldb = 1024; nloc = (bn - 80) * 64; }
  }

  const int tid = threadIdx.x, w = tid >> 6;
  const int l = tid & 63, l15 = l & 15, g4 = l >> 4;

  const __bf16* Asrc = A + (size_t)(bm * MR * 64) * K;

  f32x4 acc[MR][4];
#pragma unroll
  for (int i = 0; i < MR; ++i)
#pragma unroll
    for (int j = 0; j < 4; ++j)
#pragma unroll
      for (int r = 0; r < 4; ++r) acc[i][j][r] = 0.f;

  // B staging: TWO named reg sets (3-stage pipeline; rule-#20 static indexing)
  float4 bregA[2][2], bregB[2][2];
  const int kp_s[2] = {tid >> 4, 16 + (tid >> 4)};
  const int nn_s = (tid & 15) * 4;

  auto loadB = [&](int t, float4 (&br)[2][2]) {
    if (t >= NT) return;
#pragma unroll
    for (int p = 0; p < 2; ++p) {
      const float* src = Wsrc + (size_t)(t * 64 + 2 * kp_s[p]) * ldb + nloc + nn_s;
      br[p][0] = *(const float4*)src;
      br[p][1] = *(const float4*)(src + ldb);
    }
  };
  auto writeB = [&](float4 (&br)[2][2], unsigned* dst) {
#pragma unroll
    for (int p = 0; p < 2; ++p) {
      int kp = kp_s[p];
      int cphys = (nn_s >> 2) ^ (kp & 7);
      uint4 d;
      d.x = pack2bf(br[p][0].x, br[p][1].x);
      d.y = pack2bf(br[p][0].y, br[p][1].y);
      d.z = pack2bf(br[p][0].z, br[p][1].z);
      d.w = pack2bf(br[p][0].w, br[p][1].w);
      *(uint4*)&dst[kp * 64 + cphys * 4] = d;
    }
  };
  auto issueA = [&](int t, __bf16* dst) {
#pragma unroll
    for (int p = 0; p < MR * 2; ++p) {
      int c = p * 256 + tid;
      int row = c >> 3, gc = (c & 7) ^ (row & 7);
      gload_lds16(Asrc + (size_t)row * K + t * 64 + gc * 8, dst + (p * 256 + w * 64) * 8);
    }
  };
  auto compute = [&](const __bf16* Ab, const unsigned* Bp_) {
    bf16x8 af[MR][2];
#pragma unroll
    for (int i = 0; i < MR; ++i) {
      int m = w * MR * 16 + i * 16 + l15;
#pragma unroll
      for (int kk = 0; kk < 2; ++kk)
        af[i][kk] = *(const bf16x8*)((const char*)Ab + m * 128 + (((kk * 4 + g4) ^ (m & 7)) << 4));
    }
#pragma unroll
    for (int kk = 0; kk < 2; ++kk)
#pragma unroll
      for (int j = 0; j < 4; ++j) {
        int n = j * 16 + l15;
        union { unsigned u[4]; bf16x8 v; } fb;
#pragma unroll
        for (int d = 0; d < 4; ++d) {
          int kp = kk * 16 + g4 * 4 + d;
          fb.u[d] = Bp_[kp * 64 + (((n >> 2) ^ (kp & 7)) << 2) + (n & 3)];
        }
#pragma unroll
        for (int i = 0; i < MR; ++i)
          acc[i][j] = __builtin_amdgcn_mfma_f32_16x16x32_bf16(af[i][kk], fb.v, acc[i][j], 0, 0, 0);
      }
  };

  // prologue: B loads for tiles 0 and 1 in flight; tile 0 staged
  loadB(0, bregA);
  loadB(1, bregB);
  issueA(0, As[0]);
  writeB(bregA, Bp[0]);     // compiler inserts the vmcnt wait for breg deps
  __syncthreads();          // drains A DMA + ds_writes

  for (int t = 0; t < NT; t += 2) {
    // --- half 1: compute tile t; stage t+1; launch B loads for t+2 ---
    loadB(t + 2, bregA);    // oldest issue: ~2 k-steps before its writeB
    issueA(t + 1, As[1]);
    compute(As[0], Bp[0]);
    writeB(bregB, Bp[1]);   // tile t+1 (loaded ~2 steps ago -> landed)
    __syncthreads();
    // --- half 2: compute tile t+1; stage t+2; launch B loads for t+3 ---
    loadB(t + 3, bregB);
    if (t + 2 < NT) issueA(t + 2, As[0]);
    compute(As[1], Bp[1]);
    if (t + 2 < NT) writeB(bregA, Bp[0]);  // tile t+2
    __syncthreads();
  }

  // ---- epilogue ----
  if constexpr (MODE == 0) {
#pragma unroll
    for (int i = 0; i < MR; ++i)
#pragma unroll
      for (int j = 0; j < 4; ++j)
#pragma unroll
        for (int r = 0; r < 4; ++r) {
          size_t row = bm * MR * 64 + w * MR * 16 + i * 16 + g4 * 4 + r;
          size_t col = bn * 64 + j * 16 + l15;
          C[row * 4096 + col] = acc[i][j][r];
        }
  } else {
    if (bn < 80) {
      __bf16* dst = (bn < 64) ? Qb : Kb;
      int ldc = (bn < 64) ? 4096 : 1024;
#pragma unroll
      for (int i = 0; i < MR; ++i)
#pragma unroll
        for (int j = 0; j < 4; ++j)
#pragma unroll
          for (int r = 0; r < 4; ++r) {
            size_t row = bm * MR * 64 + w * MR * 16 + i * 16 + g4 * 4 + r;
            size_t col = (size_t)nloc + j * 16 + l15;
            dst[row * ldc + col] = (__bf16)acc[i][j][r];
          }
    } else {
      // V: write transposed -> Vt[n][s]
#pragma unroll
      for (int i = 0; i < MR; ++i)
#pragma unroll
        for (int j = 0; j < 4; ++j) {
          size_t n = (size_t)nloc + j * 16 + l15;
          size_t m0 = bm * MR * 64 + w * MR * 16 + i * 16 + g4 * 4;
          bf16x4 v;
          v.x = (__bf16)acc[i][j][0]; v.y = (__bf16)acc[i][j][1];
          v.z = (__bf16)acc[i][j][2]; v.w = (__bf16)acc[i][j][3];
          *(bf16x4*)&Vt[n * 1024 + m0] = v;
        }
    }
  }
}

// ---------------- flash attention (round-2 proven core) ----------------
// NEW (T1): 1D grid 512, XCD-localizing decode: g = b&7 pins each KV group
// (K+V = 512KB, L2-fits) to one XCD (HW round-robin b%8, m09). Bijective:
// b = g + 8*(qb*4 + hh). Core math/layout unchanged.
__global__ __launch_bounds__(256) void k_attn(const __bf16* __restrict__ Q,
                                              const __bf16* __restrict__ Kb,
                                              const __bf16* __restrict__ Vt,
                                              __bf16* __restrict__ ctx) {
  __shared__ __align__(16) char lds_raw[65536];
  __bf16* Ks = (__bf16*)lds_raw;
  __bf16* Vs = (__bf16*)(lds_raw + 32768);

  const int b = blockIdx.x;          // [0,512)
  const int g = b & 7;               // KV group, locked to XCD b%8
  const int i6 = b >> 3;             // [0,64)
  const int h = g * 4 + (i6 & 3);    // head (h>>2 == g)
  const int q0 = (i6 >> 2) * 64;     // q tile
  const int tid = threadIdx.x, w = tid >> 6, l = tid & 63;
  const int l15 = l & 15, g4 = l >> 4;
  const float scale = 0.08838834764831845f;

  bf16x8 qf[4];
  const int qrow = q0 + w * 16 + l15;
#pragma unroll
  for (int ks = 0; ks < 4; ++ks)
    qf[ks] = *(const bf16x8*)&Q[(size_t)qrow * (NH * HD) + h * HD + ks * 32 + g4 * 8];

  f32x4 acc[8];
#pragma unroll
  for (int i = 0; i < 8; ++i)
#pragma unroll
    for (int r = 0; r < 4; ++r) acc[i][r] = 0.f;
  float m_run = -__builtin_inff(), l_run = 0.f;

  const int ntiles = (q0 + 64 + 127) >> 7;
  for (int kt = 0; kt < ntiles; ++kt) {
    const int kv0 = kt * 128;
#pragma unroll
    for (int p = 0; p < 8; ++p) {
      int c = p * 256 + tid;
      int row = c >> 4, cc = c & 15;
      gload_lds16(&Kb[(size_t)(kv0 + row) * (NG * HD) + g * HD + ((cc ^ (row & 7)) << 3)],
                  &Ks[(p * 256 + w * 64) * 8]);
      gload_lds16(&Vt[(size_t)(g * HD + row) * S_LEN + kv0 + ((cc ^ (row & 7)) << 3)],
                  &Vs[(p * 256 + w * 64) * 8]);
    }
    __syncthreads();

    float sreg[8][4];
    const bool need_mask = (kv0 + 127 > q0);
#pragma unroll
    for (int tf = 0; tf < 8; ++tf) {
      f32x4 sa;
#pragma unroll
      for (int r = 0; r < 4; ++r) sa[r] = 0.f;
      int t_loc = tf * 16 + l15;
#pragma unroll
      for (int ks = 0; ks < 4; ++ks) {
        bf16x8 kf = *(const bf16x8*)((const char*)Ks + t_loc * 256 + (((ks * 4 + g4) ^ (t_loc & 7)) << 4));
        sa = __builtin_amdgcn_mfma_f32_16x16x32_bf16(kf, qf[ks], sa, 0, 0, 0);
      }
#pragma unroll
      for (int r = 0; r < 4; ++r) {
        float v = sa[r] * scale;
        if (need_mask && (kv0 + tf * 16 + g4 * 4 + r) > qrow) v = -__builtin_inff();
        sreg[tf][r] = v;
      }
    }
    float mx = -__builtin_inff();
#pragma unroll
    for (int tf = 0; tf < 8; ++tf)
#pragma unroll
      for (int r = 0; r < 4; ++r) mx = fmaxf(mx, sreg[tf][r]);
    mx = fmaxf(mx, __shfl_xor(mx, 16));
    mx = fmaxf(mx, __shfl_xor(mx, 32));
    const float m_new = fmaxf(m_run, mx);
    const float alpha = __expf(m_run - m_new);
    float ssum = 0.f;
#pragma unroll
    for (int tf = 0; tf < 8; ++tf)
#pragma unroll
      for (int r = 0; r < 4; ++r) {
        sreg[tf][r] = __expf(sreg[tf][r] - m_new);
        ssum += sreg[tf][r];
      }
    ssum += __shfl_xor(ssum, 16);
    ssum += __shfl_xor(ssum, 32);
    l_run = l_run * alpha + ssum;
    m_run = m_new;
    float ar[4];
#pragma unroll
    for (int r = 0; r < 4; ++r) ar[r] = __shfl(alpha, g4 * 4 + r);
#pragma unroll
    for (int nf = 0; nf < 8; ++nf)
#pragma unroll
      for (int r = 0; r < 4; ++r) acc[nf][r] *= ar[r];

    __syncthreads();

    char* pb = lds_raw + w * 4096;
#pragma unroll
    for (int tf = 0; tf < 8; ++tf) {
      int chunkc = 2 * tf + (g4 >> 1);
      int addr = l15 * 256 + ((chunkc ^ (l15 & 7)) << 4) + ((g4 & 1) << 3);
      *(unsigned*)(pb + addr)     = pack2bf(sreg[tf][0], sreg[tf][1]);
      *(unsigned*)(pb + addr + 4) = pack2bf(sreg[tf][2], sreg[tf][3]);
    }
    asm volatile("s_waitcnt lgkmcnt(0)" ::: "memory");
    bf16x8 pf[4];
#pragma unroll
    for (int ks = 0; ks < 4; ++ks)
      pf[ks] = *(const bf16x8*)(pb + l15 * 256 + (((ks * 4 + g4) ^ (l15 & 7)) << 4));
#pragma unroll
    for (int nf = 0; nf < 8; ++nf) {
      int d_loc = nf * 16 + l15;
#pragma unroll
      for (int ks = 0; ks < 4; ++ks) {
        bf16x8 vf = *(const bf16x8*)((const char*)Vs + d_loc * 256 + (((ks * 4 + g4) ^ (d_loc & 7)) << 4));
        acc[nf] = __builtin_amdgcn_mfma_f32_16x16x32_bf16(pf[ks], vf, acc[nf], 0, 0, 0);
      }
    }
    __syncthreads();
  }
  float li[4];
#pragma unroll
  for (int r = 0; r < 4; ++r) li[r] = 1.f / __shfl(l_run, g4 * 4 + r);
#pragma unroll
  for (int nf = 0; nf < 8; ++nf)
#pragma unroll
    for (int r = 0; r < 4; ++r) {
      size_t row = q0 + w * 16 + g4 * 4 + r;
      size_t col = (size_t)h * HD + nf * 16 + l15;
      ctx[row * (NH * HD) + col] = (__bf16)(acc[nf][r] * li[r]);
    }
}

// ---------------- host ----------------
extern "C" void kernel_launch(void* const* d_in, const int* in_sizes, int n_in,
                              void* d_out, int out_size, void* d_ws, size_t ws_size,
                              hipStream_t stream) {
  const float* x    = (const float*)d_in[0];
  const float* cosT = (const float*)d_in[2];
  const float* sinT = (const float*)d_in[3];
  const float* Wq   = (const float*)d_in[4];
  const float* Wk   = (const float*)d_in[5];
  const float* Wv   = (const float*)d_in[6];
  const float* Wo   = (const float*)d_in[7];
  float* out = (float*)d_out;

  char* ws = (char*)d_ws;
  const size_t MB = 1u << 20;
  __bf16* xb   = (__bf16*)(ws + 0);        // 8 MB : x bf16; reused as ctx after QKV
  __bf16* Qb   = (__bf16*)(ws + 8 * MB);   // 8 MB : Q, roped in-place
  __bf16* Kbuf = (__bf16*)(ws + 16 * MB);  // 2 MB : K, roped in-place
  __bf16* Vtb  = (__bf16*)(ws + 18 * MB);  // 2 MB : V^T (direct from epilogue)
  __bf16* ctxb = (__bf16*)(ws + 0);        // aliases xb (dead after QKV GEMM)

  k_cast<<<4096, 256, 0, stream>>>(x, xb, (S_LEN * DIN) / 4);

  // fused QKV: f32 weights direct, BM=256 (MR=4), 3-stage B prefetch. grid (96,4).
  k_gemm<1, 4><<<dim3(96, 4), 256, 0, stream>>>(xb, Wq, Wk, Wv, nullptr, Qb, Kbuf, Vtb);

  k_rope<<<2560, 256, 0, stream>>>(Qb, Kbuf, cosT, sinT);

  // attention: 1D grid, XCD-localized KV groups (g = blockIdx.x & 7).
  k_attn<<<512, 256, 0, stream>>>(Qb, Kbuf, Vtb, ctxb);

  // out = ctx * Wo, f32 out, BM=128 (MR=2), 3 blocks/CU. grid (64,8).
  k_gemm<0, 2><<<dim3(64, 8), 256, 0, stream>>>(ctxb, Wo, nullptr, nullptr, out,
                                                nullptr, nullptr, nullptr);
}

// Round 23
// 189.993 us; speedup vs baseline: 5.7803x; 1.0076x over previous
//
#include <hip/hip_runtime.h>
#include <hip/hip_bf16.h>

#define S_LEN 1024
#define DIN 4096
#define NH 32
#define NG 8
#define HD 128

typedef __bf16 bf16x8 __attribute__((ext_vector_type(8)));
typedef __bf16 bf16x4 __attribute__((ext_vector_type(4)));
typedef float f32x4 __attribute__((ext_vector_type(4)));

__device__ __forceinline__ void gload_lds16(const void* g, void* l) {
  __builtin_amdgcn_global_load_lds(
      (const __attribute__((address_space(1))) unsigned int*)g,
      (__attribute__((address_space(3))) unsigned int*)l, 16, 0, 0);
}

__device__ __forceinline__ unsigned pack2bf(float a, float b) {
  union { __bf16 h[2]; unsigned u; } x;
  x.h[0] = (__bf16)a; x.h[1] = (__bf16)b;
  return x.u;
}

// ---------------- cast x: f32 -> bf16 (the only prep) ----------------
__global__ __launch_bounds__(256) void k_cast(const float* __restrict__ in,
                                              __bf16* __restrict__ out, int n4) {
  int i = blockIdx.x * 256 + threadIdx.x;
  if (i >= n4) return;
  const float4 v = ((const float4*)in)[i];
  bf16x4 o;
  o.x = (__bf16)v.x; o.y = (__bf16)v.y; o.z = (__bf16)v.z; o.w = (__bf16)v.w;
  ((bf16x4*)out)[i] = o;
}

// ---------------- RoPE, vectorized: 4 d-pairs per thread ----------------
__global__ __launch_bounds__(256) void k_rope(__bf16* __restrict__ Q, __bf16* __restrict__ Kb,
                                              const float* __restrict__ cosT,
                                              const float* __restrict__ sinT) {
  int idx = blockIdx.x * 256 + threadIdx.x;
  int d = (idx & 15) * 4;
  int row = idx >> 4;
  __bf16* p; int s;
  if (row < S_LEN * NH) { p = Q + (size_t)row * HD; s = row >> 5; }
  else { int r = row - S_LEN * NH; p = Kb + (size_t)r * HD; s = r >> 3; }
  const float4 c = *(const float4*)&cosT[s * HD + d];
  const float4 sn = *(const float4*)&sinT[s * HD + d];
  bf16x4 a = *(const bf16x4*)&p[d];
  bf16x4 b = *(const bf16x4*)&p[d + 64];
  bf16x4 oa, ob;
  oa.x = (__bf16)((float)a.x * c.x - (float)b.x * sn.x);
  oa.y = (__bf16)((float)a.y * c.y - (float)b.y * sn.y);
  oa.z = (__bf16)((float)a.z * c.z - (float)b.z * sn.z);
  oa.w = (__bf16)((float)a.w * c.w - (float)b.w * sn.w);
  ob.x = (__bf16)((float)b.x * c.x + (float)a.x * sn.x);
  ob.y = (__bf16)((float)b.y * c.y + (float)a.y * sn.y);
  ob.z = (__bf16)((float)b.z * c.z + (float)a.z * sn.z);
  ob.w = (__bf16)((float)b.w * c.w + (float)a.w * sn.w);
  *(bf16x4*)&p[d] = oa;
  *(bf16x4*)&p[d + 64] = ob;
}

// ---------------- GEMM: C(M,N) = A(M,K,bf16) * W(K,N,f32) ----------------
// FINAL (r14 checkpoint, confirmed 196-201us band across r14/r19/r20/r21;
// r22 adds attention XCD swizzle -> 191.4us session best).
// Double-buffered LDS, 3-stage B prefetch, plain __syncthreads.
// Falsified alternatives: hand-vmcnt (r15 +22us), MR=8 (r16 +34), 4 blk/CU
// (r17 spills), single-buffer (r18 +30/dispatch), XCD remap on GEMM (r13 +21),
// QKV MR=2 (r20 +11).
// B: reg-staged f32, k-pair packed, b128 to Bp[kp][16c][4] at
//    cphys=(nn>>2)^(kp&7) [0 conflicts measured].
// A: DMA-staged bf16, XOR chunk swizzle [0 conflicts measured].
// MODE 0 (MR=2): f32 C, grid (64,8), 48KB LDS -> 3 blocks/CU.
// MODE 1 (MR=4): QKV split, grid (96,4), 80KB LDS -> 2 blocks/CU.
template <int MODE, int MR>
__global__ __launch_bounds__(256, (MR == 2) ? 3 : 2)
void k_gemm(const __bf16* __restrict__ A,
            const float* __restrict__ W0,
            const float* __restrict__ W1,
            const float* __restrict__ W2,
            float* __restrict__ C,
            __bf16* __restrict__ Qb,
            __bf16* __restrict__ Kb,
            __bf16* __restrict__ Vt) {
  __shared__ __bf16 As[2][MR * 64 * 64];
  __shared__ unsigned Bp[2][32 * 64];
  const int bm = blockIdx.y, bn = blockIdx.x;
  const int K = DIN, NT = K / 64;

  const float* Wsrc; int ldb, nloc;
  if (MODE == 0) { Wsrc = W0; ldb = 4096; nloc = bn * 64; }
  else {
    if (bn < 64)      { Wsrc = W0; ldb = 4096; nloc = bn * 64; }
    else if (bn < 80) { Wsrc = W1; ldb = 1024; nloc = (bn - 64) * 64; }
    else              { Wsrc = W2; ldb = 1024; nloc = (bn - 80) * 64; }
  }

  const int tid = threadIdx.x, w = tid >> 6;
  const int l = tid & 63, l15 = l & 15, g4 = l >> 4;

  const __bf16* Asrc = A + (size_t)(bm * MR * 64) * K;

  f32x4 acc[MR][4];
#pragma unroll
  for (int i = 0; i < MR; ++i)
#pragma unroll
    for (int j = 0; j < 4; ++j)
#pragma unroll
      for (int r = 0; r < 4; ++r) acc[i][j][r] = 0.f;

  // B staging: TWO named reg sets (3-stage pipeline; rule-#20 static indexing)
  float4 bregA[2][2], bregB[2][2];
  const int kp_s[2] = {tid >> 4, 16 + (tid >> 4)};
  const int nn_s = (tid & 15) * 4;

  auto loadB = [&](int t, float4 (&br)[2][2]) {
    if (t >= NT) return;
#pragma unroll
    for (int p = 0; p < 2; ++p) {
      const float* src = Wsrc + (size_t)(t * 64 + 2 * kp_s[p]) * ldb + nloc + nn_s;
      br[p][0] = *(const float4*)src;
      br[p][1] = *(const float4*)(src + ldb);
    }
  };
  auto writeB = [&](float4 (&br)[2][2], unsigned* dst) {
#pragma unroll
    for (int p = 0; p < 2; ++p) {
      int kp = kp_s[p];
      int cphys = (nn_s >> 2) ^ (kp & 7);
      uint4 d;
      d.x = pack2bf(br[p][0].x, br[p][1].x);
      d.y = pack2bf(br[p][0].y, br[p][1].y);
      d.z = pack2bf(br[p][0].z, br[p][1].z);
      d.w = pack2bf(br[p][0].w, br[p][1].w);
      *(uint4*)&dst[kp * 64 + cphys * 4] = d;
    }
  };
  auto issueA = [&](int t, __bf16* dst) {
#pragma unroll
    for (int p = 0; p < MR * 2; ++p) {
      int c = p * 256 + tid;
      int row = c >> 3, gc = (c & 7) ^ (row & 7);
      gload_lds16(Asrc + (size_t)row * K + t * 64 + gc * 8, dst + (p * 256 + w * 64) * 8);
    }
  };
  auto compute = [&](const __bf16* Ab, const unsigned* Bp_) {
    bf16x8 af[MR][2];
#pragma unroll
    for (int i = 0; i < MR; ++i) {
      int m = w * MR * 16 + i * 16 + l15;
#pragma unroll
      for (int kk = 0; kk < 2; ++kk)
        af[i][kk] = *(const bf16x8*)((const char*)Ab + m * 128 + (((kk * 4 + g4) ^ (m & 7)) << 4));
    }
#pragma unroll
    for (int kk = 0; kk < 2; ++kk)
#pragma unroll
      for (int j = 0; j < 4; ++j) {
        int n = j * 16 + l15;
        union { unsigned u[4]; bf16x8 v; } fb;
#pragma unroll
        for (int d = 0; d < 4; ++d) {
          int kp = kk * 16 + g4 * 4 + d;
          fb.u[d] = Bp_[kp * 64 + (((n >> 2) ^ (kp & 7)) << 2) + (n & 3)];
        }
#pragma unroll
        for (int i = 0; i < MR; ++i)
          acc[i][j] = __builtin_amdgcn_mfma_f32_16x16x32_bf16(af[i][kk], fb.v, acc[i][j], 0, 0, 0);
      }
  };

  // prologue: B loads for tiles 0 and 1 in flight; tile 0 staged
  loadB(0, bregA);
  loadB(1, bregB);
  issueA(0, As[0]);
  writeB(bregA, Bp[0]);     // compiler inserts the vmcnt wait for breg deps
  __syncthreads();          // drains A DMA + ds_writes

  for (int t = 0; t < NT; t += 2) {
    // --- half 1: compute tile t; stage t+1; launch B loads for t+2 ---
    loadB(t + 2, bregA);    // oldest issue: ~2 k-steps before its writeB
    issueA(t + 1, As[1]);
    compute(As[0], Bp[0]);
    writeB(bregB, Bp[1]);   // tile t+1 (loaded ~2 steps ago -> landed)
    __syncthreads();
    // --- half 2: compute tile t+1; stage t+2; launch B loads for t+3 ---
    loadB(t + 3, bregB);
    if (t + 2 < NT) issueA(t + 2, As[0]);
    compute(As[1], Bp[1]);
    if (t + 2 < NT) writeB(bregA, Bp[0]);  // tile t+2
    __syncthreads();
  }

  // ---- epilogue ----
  if constexpr (MODE == 0) {
#pragma unroll
    for (int i = 0; i < MR; ++i)
#pragma unroll
      for (int j = 0; j < 4; ++j)
#pragma unroll
        for (int r = 0; r < 4; ++r) {
          size_t row = bm * MR * 64 + w * MR * 16 + i * 16 + g4 * 4 + r;
          size_t col = bn * 64 + j * 16 + l15;
          C[row * 4096 + col] = acc[i][j][r];
        }
  } else {
    if (bn < 80) {
      __bf16* dst = (bn < 64) ? Qb : Kb;
      int ldc = (bn < 64) ? 4096 : 1024;
#pragma unroll
      for (int i = 0; i < MR; ++i)
#pragma unroll
        for (int j = 0; j < 4; ++j)
#pragma unroll
          for (int r = 0; r < 4; ++r) {
            size_t row = bm * MR * 64 + w * MR * 16 + i * 16 + g4 * 4 + r;
            size_t col = (size_t)nloc + j * 16 + l15;
            dst[row * ldc + col] = (__bf16)acc[i][j][r];
          }
    } else {
      // V: write transposed -> Vt[n][s]
#pragma unroll
      for (int i = 0; i < MR; ++i)
#pragma unroll
        for (int j = 0; j < 4; ++j) {
          size_t n = (size_t)nloc + j * 16 + l15;
          size_t m0 = bm * MR * 64 + w * MR * 16 + i * 16 + g4 * 4;
          bf16x4 v;
          v.x = (__bf16)acc[i][j][0]; v.y = (__bf16)acc[i][j][1];
          v.z = (__bf16)acc[i][j][2]; v.w = (__bf16)acc[i][j][3];
          *(bf16x4*)&Vt[n * 1024 + m0] = v;
        }
    }
  }
}

// ---------------- flash attention ----------------
// r22: 1D grid 512, XCD-localized KV groups (g = b&7; K+V = 512KB L2-fits
// per XCD; measured -5us). NEW (T5): s_setprio(1) around the QK^T and PV
// MFMA clusters — 2 blocks/CU at independent phases gives the scheduler
// role diversity (m191 attention regime, not m190 lockstep null).
__global__ __launch_bounds__(256) void k_attn(const __bf16* __restrict__ Q,
                                              const __bf16* __restrict__ Kb,
                                              const __bf16* __restrict__ Vt,
                                              __bf16* __restrict__ ctx) {
  __shared__ __align__(16) char lds_raw[65536];
  __bf16* Ks = (__bf16*)lds_raw;
  __bf16* Vs = (__bf16*)(lds_raw + 32768);

  const int b = blockIdx.x;          // [0,512)
  const int g = b & 7;               // KV group, locked to XCD b%8
  const int i6 = b >> 3;             // [0,64)
  const int h = g * 4 + (i6 & 3);    // head (h>>2 == g)
  const int q0 = (i6 >> 2) * 64;     // q tile
  const int tid = threadIdx.x, w = tid >> 6, l = tid & 63;
  const int l15 = l & 15, g4 = l >> 4;
  const float scale = 0.08838834764831845f;

  bf16x8 qf[4];
  const int qrow = q0 + w * 16 + l15;
#pragma unroll
  for (int ks = 0; ks < 4; ++ks)
    qf[ks] = *(const bf16x8*)&Q[(size_t)qrow * (NH * HD) + h * HD + ks * 32 + g4 * 8];

  f32x4 acc[8];
#pragma unroll
  for (int i = 0; i < 8; ++i)
#pragma unroll
    for (int r = 0; r < 4; ++r) acc[i][r] = 0.f;
  float m_run = -__builtin_inff(), l_run = 0.f;

  const int ntiles = (q0 + 64 + 127) >> 7;
  for (int kt = 0; kt < ntiles; ++kt) {
    const int kv0 = kt * 128;
#pragma unroll
    for (int p = 0; p < 8; ++p) {
      int c = p * 256 + tid;
      int row = c >> 4, cc = c & 15;
      gload_lds16(&Kb[(size_t)(kv0 + row) * (NG * HD) + g * HD + ((cc ^ (row & 7)) << 3)],
                  &Ks[(p * 256 + w * 64) * 8]);
      gload_lds16(&Vt[(size_t)(g * HD + row) * S_LEN + kv0 + ((cc ^ (row & 7)) << 3)],
                  &Vs[(p * 256 + w * 64) * 8]);
    }
    __syncthreads();

    float sreg[8][4];
    const bool need_mask = (kv0 + 127 > q0);
    __builtin_amdgcn_s_setprio(1);   // T5: QK^T MFMA cluster
#pragma unroll
    for (int tf = 0; tf < 8; ++tf) {
      f32x4 sa;
#pragma unroll
      for (int r = 0; r < 4; ++r) sa[r] = 0.f;
      int t_loc = tf * 16 + l15;
#pragma unroll
      for (int ks = 0; ks < 4; ++ks) {
        bf16x8 kf = *(const bf16x8*)((const char*)Ks + t_loc * 256 + (((ks * 4 + g4) ^ (t_loc & 7)) << 4));
        sa = __builtin_amdgcn_mfma_f32_16x16x32_bf16(kf, qf[ks], sa, 0, 0, 0);
      }
#pragma unroll
      for (int r = 0; r < 4; ++r) {
        float v = sa[r] * scale;
        if (need_mask && (kv0 + tf * 16 + g4 * 4 + r) > qrow) v = -__builtin_inff();
        sreg[tf][r] = v;
      }
    }
    __builtin_amdgcn_s_setprio(0);
    float mx = -__builtin_inff();
#pragma unroll
    for (int tf = 0; tf < 8; ++tf)
#pragma unroll
      for (int r = 0; r < 4; ++r) mx = fmaxf(mx, sreg[tf][r]);
    mx = fmaxf(mx, __shfl_xor(mx, 16));
    mx = fmaxf(mx, __shfl_xor(mx, 32));
    const float m_new = fmaxf(m_run, mx);
    const float alpha = __expf(m_run - m_new);
    float ssum = 0.f;
#pragma unroll
    for (int tf = 0; tf < 8; ++tf)
#pragma unroll
      for (int r = 0; r < 4; ++r) {
        sreg[tf][r] = __expf(sreg[tf][r] - m_new);
        ssum += sreg[tf][r];
      }
    ssum += __shfl_xor(ssum, 16);
    ssum += __shfl_xor(ssum, 32);
    l_run = l_run * alpha + ssum;
    m_run = m_new;
    float ar[4];
#pragma unroll
    for (int r = 0; r < 4; ++r) ar[r] = __shfl(alpha, g4 * 4 + r);
#pragma unroll
    for (int nf = 0; nf < 8; ++nf)
#pragma unroll
      for (int r = 0; r < 4; ++r) acc[nf][r] *= ar[r];

    __syncthreads();

    char* pb = lds_raw + w * 4096;
#pragma unroll
    for (int tf = 0; tf < 8; ++tf) {
      int chunkc = 2 * tf + (g4 >> 1);
      int addr = l15 * 256 + ((chunkc ^ (l15 & 7)) << 4) + ((g4 & 1) << 3);
      *(unsigned*)(pb + addr)     = pack2bf(sreg[tf][0], sreg[tf][1]);
      *(unsigned*)(pb + addr + 4) = pack2bf(sreg[tf][2], sreg[tf][3]);
    }
    asm volatile("s_waitcnt lgkmcnt(0)" ::: "memory");
    bf16x8 pf[4];
#pragma unroll
    for (int ks = 0; ks < 4; ++ks)
      pf[ks] = *(const bf16x8*)(pb + l15 * 256 + (((ks * 4 + g4) ^ (l15 & 7)) << 4));
    __builtin_amdgcn_s_setprio(1);   // T5: PV MFMA cluster
#pragma unroll
    for (int nf = 0; nf < 8; ++nf) {
      int d_loc = nf * 16 + l15;
#pragma unroll
      for (int ks = 0; ks < 4; ++ks) {
        bf16x8 vf = *(const bf16x8*)((const char*)Vs + d_loc * 256 + (((ks * 4 + g4) ^ (d_loc & 7)) << 4));
        acc[nf] = __builtin_amdgcn_mfma_f32_16x16x32_bf16(pf[ks], vf, acc[nf], 0, 0, 0);
      }
    }
    __builtin_amdgcn_s_setprio(0);
    __syncthreads();
  }
  float li[4];
#pragma unroll
  for (int r = 0; r < 4; ++r) li[r] = 1.f / __shfl(l_run, g4 * 4 + r);
#pragma unroll
  for (int nf = 0; nf < 8; ++nf)
#pragma unroll
    for (int r = 0; r < 4; ++r) {
      size_t row = q0 + w * 16 + g4 * 4 + r;
      size_t col = (size_t)h * HD + nf * 16 + l15;
      ctx[row * (NH * HD) + col] = (__bf16)(acc[nf][r] * li[r]);
    }
}

// ---------------- host ----------------
extern "C" void kernel_launch(void* const* d_in, const int* in_sizes, int n_in,
                              void* d_out, int out_size, void* d_ws, size_t ws_size,
                              hipStream_t stream) {
  const float* x    = (const float*)d_in[0];
  const float* cosT = (const float*)d_in[2];
  const float* sinT = (const float*)d_in[3];
  const float* Wq   = (const float*)d_in[4];
  const float* Wk   = (const float*)d_in[5];
  const float* Wv   = (const float*)d_in[6];
  const float* Wo   = (const float*)d_in[7];
  float* out = (float*)d_out;

  char* ws = (char*)d_ws;
  const size_t MB = 1u << 20;
  __bf16* xb   = (__bf16*)(ws + 0);        // 8 MB : x bf16; reused as ctx after QKV
  __bf16* Qb   = (__bf16*)(ws + 8 * MB);   // 8 MB : Q, roped in-place
  __bf16* Kbuf = (__bf16*)(ws + 16 * MB);  // 2 MB : K, roped in-place
  __bf16* Vtb  = (__bf16*)(ws + 18 * MB);  // 2 MB : V^T (direct from epilogue)
  __bf16* ctxb = (__bf16*)(ws + 0);        // aliases xb (dead after QKV GEMM)

  k_cast<<<4096, 256, 0, stream>>>(x, xb, (S_LEN * DIN) / 4);

  // fused QKV: f32 weights direct, BM=256 (MR=4), 3-stage B prefetch. grid (96,4).
  k_gemm<1, 4><<<dim3(96, 4), 256, 0, stream>>>(xb, Wq, Wk, Wv, nullptr, Qb, Kbuf, Vtb);

  k_rope<<<2560, 256, 0, stream>>>(Qb, Kbuf, cosT, sinT);

  // attention: 1D grid, XCD-localized KV groups + T5 setprio.
  k_attn<<<512, 256, 0, stream>>>(Qb, Kbuf, Vtb, ctxb);

  // out = ctx * Wo, f32 out, BM=128 (MR=2), 3 blocks/CU. grid (64,8).
  k_gemm<0, 2><<<dim3(64, 8), 256, 0, stream>>>(ctxb, Wo, nullptr, nullptr, out,
                                                nullptr, nullptr, nullptr);
}